// Round 4
// baseline (743.010 us; speedup 1.0000x reference)
//
#include <hip/hip_runtime.h>

typedef unsigned short u16;
typedef unsigned int u32;

#define BATCH 2
#define TTEXT 2048
#define DIM 1024
#define TMED 8
#define MTOK 256
#define HEADS 16
#define DHEAD 64
#define INNER 1024
#define TM 2048            // TMED * MTOK
#define QSCALE 0.125f      // DHEAD^-0.5

// ---------------- text_time = cumsum(media_locations) ----------------
// Dtype-agnostic: detect 1-byte bool vs 4-byte storage from the first 4096
// bytes (safe under both layouts). Byte-bool -> whole tensor in 4096 bytes
// -> 16 nonzero bytes; 4-byte elems -> first 1024 elems of row 0 -> <= 8
// nonzero ints (bool as int32: <=8 nonzero bytes; as float32 1.0f: <=16,
// but >=9 only if >=5 trues in first half of row 0 -- and float32 4-byte
// reads via as_int are ALSO correct, so misdetection risk only matters for
// true byte storage, where count is exactly 16).
__global__ __launch_bounds__(256) void scan_kernel(const unsigned char* __restrict__ raw,
                                                   int* __restrict__ tt){
  int t = threadIdx.x;
  __shared__ int sd[256];
  int c = 0;
  for (int i = t; i < 4096; i += 256) c += (raw[i] != 0);
  sd[t] = c; __syncthreads();
  for (int off = 128; off; off >>= 1){
    if (t < off) sd[t] += sd[t + off];
    __syncthreads();
  }
  int is_byte = (sd[0] >= 9);
  __syncthreads();
  const int* as_int = (const int*)raw;
  for (int b = 0; b < BATCH; b++){
    int inc[8]; int s = 0;
    #pragma unroll
    for (int k = 0; k < 8; k++){
      int i = b * TTEXT + t * 8 + k;
      int v = is_byte ? (raw[i] != 0) : (as_int[i] != 0);
      s += v; inc[k] = s;
    }
    sd[t] = s; __syncthreads();
    for (int off = 1; off < 256; off <<= 1){
      int v = (t >= off) ? sd[t - off] : 0;
      __syncthreads();
      sd[t] += v;
      __syncthreads();
    }
    int excl = sd[t] - s;
    #pragma unroll
    for (int k = 0; k < 8; k++) tt[b * TTEXT + t * 8 + k] = excl + inc[k];
    __syncthreads();
  }
}

// ---------------- LayerNorm: x(fp32) -> xn(fp32) ----------------
__global__ __launch_bounds__(256) void ln_kernel(const float* __restrict__ x,
                                                 const float* __restrict__ gamma,
                                                 const float* __restrict__ beta,
                                                 float* __restrict__ xn){
  int row = blockIdx.x, t = threadIdx.x;
  float4 v = *(const float4*)(x + (size_t)row * DIM + t * 4);
  float s  = v.x + v.y + v.z + v.w;
  float ss = v.x*v.x + v.y*v.y + v.z*v.z + v.w*v.w;
  #pragma unroll
  for (int off = 32; off; off >>= 1){ s += __shfl_xor(s, off); ss += __shfl_xor(ss, off); }
  __shared__ float ps[4], pss[4];
  __shared__ float mu_s, rs_s;
  int w = t >> 6;
  if ((t & 63) == 0){ ps[w] = s; pss[w] = ss; }
  __syncthreads();
  if (t == 0){
    float S = ps[0] + ps[1] + ps[2] + ps[3];
    float SS = pss[0] + pss[1] + pss[2] + pss[3];
    float mu = S * (1.f / DIM);
    float var = SS * (1.f / DIM) - mu * mu;
    mu_s = mu; rs_s = rsqrtf(var + 1e-5f);
  }
  __syncthreads();
  float mu = mu_s, rs = rs_s;
  float4 g  = *(const float4*)(gamma + t * 4);
  float4 be = *(const float4*)(beta + t * 4);
  float4 o;
  o.x = (v.x - mu) * rs * g.x + be.x;
  o.y = (v.y - mu) * rs * g.y + be.y;
  o.z = (v.z - mu) * rs * g.z + be.z;
  o.w = (v.w - mu) * rs * g.w + be.w;
  *(float4*)(xn + (size_t)row * DIM + t * 4) = o;
}

// ---------------- GEMM: C[M,N] = A[M,K] @ B[K,N], fp32 ----------------
// MODE 1: store fp32 C.  MODE 2: kv-scatter fp32 (Cp=kT, C2p=v).
// 128x128 tile, BK=16, 256 threads, 8x8 per thread. All dims divide evenly here.
template<int MODE>
__global__ __launch_bounds__(256) void gemm_k(const float* __restrict__ Ap,
                                              const float* __restrict__ Bp,
                                              void* __restrict__ Cp,
                                              float* __restrict__ C2p,
                                              int M, int N, int K){
  __shared__ float As[16][136];
  __shared__ float Bs[16][136];
  int tid = threadIdx.x;
  int m0 = blockIdx.x * 128, n0 = blockIdx.y * 128;
  int ty = tid >> 4, tx = tid & 15;
  int arow = tid >> 1, aseg = tid & 1;
  int brow = tid >> 4, bcol = (tid & 15) * 8;
  float acc[8][8];
  #pragma unroll
  for (int i = 0; i < 8; i++)
    #pragma unroll
    for (int j = 0; j < 8; j++) acc[i][j] = 0.f;

  for (int k0 = 0; k0 < K; k0 += 16){
    const float* bp = Bp + (size_t)(k0 + brow) * N + n0 + bcol;
    float4 b0 = *(const float4*)(bp);
    float4 b1 = *(const float4*)(bp + 4);
    *(float4*)&Bs[brow][bcol]     = b0;
    *(float4*)&Bs[brow][bcol + 4] = b1;
    const float* ap = Ap + (size_t)(m0 + arow) * K + k0 + aseg * 8;
    float4 a0 = *(const float4*)(ap);
    float4 a1 = *(const float4*)(ap + 4);
    int kb = aseg * 8;
    As[kb+0][arow] = a0.x; As[kb+1][arow] = a0.y;
    As[kb+2][arow] = a0.z; As[kb+3][arow] = a0.w;
    As[kb+4][arow] = a1.x; As[kb+5][arow] = a1.y;
    As[kb+6][arow] = a1.z; As[kb+7][arow] = a1.w;
    __syncthreads();
    #pragma unroll
    for (int kk = 0; kk < 16; kk++){
      float a[8], b[8];
      float4 x0 = *(const float4*)&As[kk][ty*8];
      float4 x1 = *(const float4*)&As[kk][ty*8 + 4];
      a[0]=x0.x; a[1]=x0.y; a[2]=x0.z; a[3]=x0.w;
      a[4]=x1.x; a[5]=x1.y; a[6]=x1.z; a[7]=x1.w;
      float4 y0 = *(const float4*)&Bs[kk][tx*8];
      float4 y1 = *(const float4*)&Bs[kk][tx*8 + 4];
      b[0]=y0.x; b[1]=y0.y; b[2]=y0.z; b[3]=y0.w;
      b[4]=y1.x; b[5]=y1.y; b[6]=y1.z; b[7]=y1.w;
      #pragma unroll
      for (int i = 0; i < 8; i++)
        #pragma unroll
        for (int j = 0; j < 8; j++) acc[i][j] += a[i] * b[j];
    }
    __syncthreads();
  }

  if (MODE == 1){
    float* C = (float*)Cp;
    #pragma unroll
    for (int i = 0; i < 8; i++){
      int r = m0 + ty*8 + i;
      float* cr = C + (size_t)r * N + n0 + tx*8;
      *(float4*)cr       = make_float4(acc[i][0], acc[i][1], acc[i][2], acc[i][3]);
      *(float4*)(cr + 4) = make_float4(acc[i][4], acc[i][5], acc[i][6], acc[i][7]);
    }
  } else {
    float* Kt = (float*)Cp;
    float* Vb = C2p;
    #pragma unroll
    for (int i = 0; i < 8; i++){
      int r = m0 + ty*8 + i;
      int bb = r >> 11, jj = r & 2047;
      #pragma unroll
      for (int j = 0; j < 8; j++){
        int c = n0 + tx*8 + j;
        float val = acc[i][j];
        if (c < INNER){
          int hh = c >> 6, dd = c & 63;
          Kt[(((size_t)bb * HEADS + hh) * DHEAD + dd) * TM + jj] = val;
        } else {
          int cc = c - INNER;
          int hh = cc >> 6, dd = cc & 63;
          Vb[(((size_t)bb * HEADS + hh) * TM + jj) * DHEAD + dd] = val;
        }
      }
    }
  }
}

// ---------------- attention: 16 queries x 1 head per block ----------------
__global__ __launch_bounds__(256) void attn_kernel(const float* __restrict__ qb,
                                                   const float* __restrict__ kT,
                                                   const float* __restrict__ vB,
                                                   const int* __restrict__ tt,
                                                   float* __restrict__ ao){
  int t = threadIdx.x;
  int chunk = blockIdx.x & 127;
  int b = blockIdx.x >> 7;
  int h = blockIdx.y;
  int q0 = chunk * 16;
  __shared__ float qsT[64][16];
  __shared__ float Pb[16][256];
  __shared__ int miq[16];
  __shared__ int present[8];
  __shared__ float mxA[16], smA[16];
  if (t < 8) present[t] = 0;
  __syncthreads();
  if (t < 16){
    int v = tt[b * TTEXT + q0 + t] - 1;
    miq[t] = v;
    if (v >= 0 && v < 8) present[v] = 1;   // clamp guards shared OOB
  }
  for (int e = t; e < 1024; e += 256){
    int qq = e >> 6, dd = e & 63;
    qsT[dd][qq] = qb[(size_t)(b * TTEXT + q0 + qq) * INNER + h * DHEAD + dd] * QSCALE;
  }
  __syncthreads();
  int j = t;
  int w = t >> 6, lane = t & 63;
  int d = t & 63, g = t >> 6;
  for (int mi = 0; mi < 8; mi++){
    if (!present[mi]) continue;          // uniform across block
    float s[16];
    #pragma unroll
    for (int q = 0; q < 16; q++) s[q] = 0.f;
    const float* kp = kT + ((size_t)(b * HEADS + h) * DHEAD) * TM + mi * MTOK + j;
    for (int dd = 0; dd < 64; dd++){
      float kv = kp[(size_t)dd * TM];
      const float4* qr = (const float4*)&qsT[dd][0];
      float4 qv0 = qr[0], qv1 = qr[1], qv2 = qr[2], qv3 = qr[3];
      s[0]  += qv0.x * kv; s[1]  += qv0.y * kv; s[2]  += qv0.z * kv; s[3]  += qv0.w * kv;
      s[4]  += qv1.x * kv; s[5]  += qv1.y * kv; s[6]  += qv1.z * kv; s[7]  += qv1.w * kv;
      s[8]  += qv2.x * kv; s[9]  += qv2.y * kv; s[10] += qv2.z * kv; s[11] += qv2.w * kv;
      s[12] += qv3.x * kv; s[13] += qv3.y * kv; s[14] += qv3.z * kv; s[15] += qv3.w * kv;
    }
    #pragma unroll
    for (int q = 0; q < 16; q++) Pb[q][j] = s[q];
    __syncthreads();
    #pragma unroll
    for (int qq = 0; qq < 4; qq++){
      int q = w * 4 + qq;
      float v0 = Pb[q][lane], v1 = Pb[q][lane+64], v2 = Pb[q][lane+128], v3 = Pb[q][lane+192];
      float m = fmaxf(fmaxf(v0, v1), fmaxf(v2, v3));
      #pragma unroll
      for (int off = 32; off; off >>= 1) m = fmaxf(m, __shfl_xor(m, off));
      float e = __expf(v0 - m) + __expf(v1 - m) + __expf(v2 - m) + __expf(v3 - m);
      #pragma unroll
      for (int off = 32; off; off >>= 1) e += __shfl_xor(e, off);
      if (lane == 0){ mxA[q] = m; smA[q] = 1.f / e; }
    }
    __syncthreads();
    #pragma unroll
    for (int q = 0; q < 16; q++) Pb[q][j] = __expf(s[q] - mxA[q]) * smA[q];
    __syncthreads();
    float o[4] = {0.f, 0.f, 0.f, 0.f};
    const float* vp = vB + ((size_t)(b * HEADS + h) * TM + mi * MTOK) * DHEAD + d;
    for (int jj = 0; jj < 256; jj += 4){
      float vv0 = vp[(size_t)(jj + 0) * DHEAD];
      float vv1 = vp[(size_t)(jj + 1) * DHEAD];
      float vv2 = vp[(size_t)(jj + 2) * DHEAD];
      float vv3 = vp[(size_t)(jj + 3) * DHEAD];
      #pragma unroll
      for (int qq = 0; qq < 4; qq++){
        int q = g * 4 + qq;
        float4 p4 = *(const float4*)&Pb[q][jj];
        o[qq] += p4.x * vv0 + p4.y * vv1 + p4.z * vv2 + p4.w * vv3;
      }
    }
    #pragma unroll
    for (int qq = 0; qq < 4; qq++){
      int q = g * 4 + qq;
      if (miq[q] == mi)
        ao[(size_t)(b * TTEXT + q0 + q) * INNER + h * DHEAD + d] = o[qq];
    }
    __syncthreads();
  }
  #pragma unroll
  for (int qq = 0; qq < 4; qq++){
    int q = g * 4 + qq;
    if (miq[q] < 0 || miq[q] > 7)
      ao[(size_t)(b * TTEXT + q0 + q) * INNER + h * DHEAD + d] = 0.f;
  }
}

extern "C" void kernel_launch(void* const* d_in, const int* in_sizes, int n_in,
                              void* d_out, int out_size, void* d_ws, size_t ws_size,
                              hipStream_t stream){
  const float* x      = (const float*)d_in[0];
  const float* media  = (const float*)d_in[1];
  const unsigned char* locs = (const unsigned char*)d_in[2];
  const float* gamma  = (const float*)d_in[3];
  const float* beta   = (const float*)d_in[4];
  const float* Wq     = (const float*)d_in[5];
  const float* Wkv    = (const float*)d_in[6];
  const float* Wout   = (const float*)d_in[7];

  // workspace layout (~80 MB)
  char* ws = (char*)d_ws;
  int* tt   = (int*)ws;        ws += 16384;
  float* xn = (float*)ws;      ws += (size_t)4096 * 1024 * 4;   // [B*T, DIM]
  float* qb = (float*)ws;      ws += (size_t)4096 * 1024 * 4;   // [B*T, INNER]
  float* kT = (float*)ws;      ws += (size_t)4096 * 1024 * 4;   // [B,H,64,TM]
  float* vB = (float*)ws;      ws += (size_t)4096 * 1024 * 4;   // [B,H,TM,64]
  float* ao = (float*)ws;      ws += (size_t)4096 * 1024 * 4;   // [B*T, INNER]

  scan_kernel<<<1, 256, 0, stream>>>(locs, tt);
  ln_kernel<<<BATCH * TTEXT, 256, 0, stream>>>(x, gamma, beta, xn);
  gemm_k<1><<<dim3(32, 8),  256, 0, stream>>>(xn,    Wq,   qb,    nullptr, 4096, 1024, 1024);
  gemm_k<2><<<dim3(32, 16), 256, 0, stream>>>(media, Wkv,  kT,    vB,      4096, 2048, 1024);
  attn_kernel<<<dim3(256, 16), 256, 0, stream>>>(qb, kT, vB, tt, ao);
  gemm_k<1><<<dim3(32, 8),  256, 0, stream>>>(ao,    Wout, d_out, nullptr, 4096, 1024, 1024);
}

// Round 5
// 340.198 us; speedup vs baseline: 2.1841x; 2.1841x over previous
//
#include <hip/hip_runtime.h>

typedef unsigned short u16;
typedef unsigned int u32;

#define BATCH 2
#define TTEXT 2048
#define DIM 1024
#define TMED 8
#define MTOK 256
#define HEADS 16
#define DHEAD 64
#define INNER 1024
#define TM 2048            // TMED * MTOK
#define QSCALE 0.125f      // DHEAD^-0.5

typedef __attribute__((ext_vector_type(8))) short bf16x8;
typedef __attribute__((ext_vector_type(4))) float f32x4;

__device__ __forceinline__ float b2f(u16 u){
  union { float f; u32 i; } x; x.i = ((u32)u) << 16; return x.f;
}
__device__ __forceinline__ u16 f2b(float f){
  union { float f; u32 i; } x; x.f = f;
  u32 r = x.i + 0x7FFFu + ((x.i >> 16) & 1u);   // RNE
  return (u16)(r >> 16);
}

#define GLDS16(g, l) __builtin_amdgcn_global_load_lds( \
    (const __attribute__((address_space(1))) u32*)(g), \
    (__attribute__((address_space(3))) u32*)(l), 16, 0, 0)

// ---------------- text_time = cumsum(media_locations) ----------------
__global__ __launch_bounds__(256) void scan_kernel(const unsigned char* __restrict__ raw,
                                                   int* __restrict__ tt){
  int t = threadIdx.x;
  __shared__ int sd[256];
  int c = 0;
  for (int i = t; i < 4096; i += 256) c += (raw[i] != 0);
  sd[t] = c; __syncthreads();
  for (int off = 128; off; off >>= 1){
    if (t < off) sd[t] += sd[t + off];
    __syncthreads();
  }
  int is_byte = (sd[0] >= 9);
  __syncthreads();
  const int* as_int = (const int*)raw;
  for (int b = 0; b < BATCH; b++){
    int inc[8]; int s = 0;
    #pragma unroll
    for (int k = 0; k < 8; k++){
      int i = b * TTEXT + t * 8 + k;
      int v = is_byte ? (raw[i] != 0) : (as_int[i] != 0);
      s += v; inc[k] = s;
    }
    sd[t] = s; __syncthreads();
    for (int off = 1; off < 256; off <<= 1){
      int v = (t >= off) ? sd[t - off] : 0;
      __syncthreads();
      sd[t] += v;
      __syncthreads();
    }
    int excl = sd[t] - s;
    #pragma unroll
    for (int k = 0; k < 8; k++) tt[b * TTEXT + t * 8 + k] = excl + inc[k];
    __syncthreads();
  }
}

// ---------------- LayerNorm: x(fp32) -> xn(bf16) ----------------
__global__ __launch_bounds__(256) void ln_kernel(const float* __restrict__ x,
                                                 const float* __restrict__ gamma,
                                                 const float* __restrict__ beta,
                                                 u16* __restrict__ xn){
  int row = blockIdx.x, t = threadIdx.x;
  float4 v = *(const float4*)(x + (size_t)row * DIM + t * 4);
  float s  = v.x + v.y + v.z + v.w;
  float ss = v.x*v.x + v.y*v.y + v.z*v.z + v.w*v.w;
  #pragma unroll
  for (int off = 32; off; off >>= 1){ s += __shfl_xor(s, off); ss += __shfl_xor(ss, off); }
  __shared__ float ps[4], pss[4];
  __shared__ float mu_s, rs_s;
  int w = t >> 6;
  if ((t & 63) == 0){ ps[w] = s; pss[w] = ss; }
  __syncthreads();
  if (t == 0){
    float S = ps[0] + ps[1] + ps[2] + ps[3];
    float SS = pss[0] + pss[1] + pss[2] + pss[3];
    float mu = S * (1.f / DIM);
    float var = SS * (1.f / DIM) - mu * mu;
    mu_s = mu; rs_s = rsqrtf(var + 1e-5f);
  }
  __syncthreads();
  float mu = mu_s, rs = rs_s;
  float4 g  = *(const float4*)(gamma + t * 4);
  float4 be = *(const float4*)(beta + t * 4);
  ushort4 o;
  o.x = f2b((v.x - mu) * rs * g.x + be.x);
  o.y = f2b((v.y - mu) * rs * g.y + be.y);
  o.z = f2b((v.z - mu) * rs * g.z + be.z);
  o.w = f2b((v.w - mu) * rs * g.w + be.w);
  *(ushort4*)(xn + (size_t)row * DIM + t * 4) = o;
}

// ---------------- fp32 -> bf16 elementwise (media) ----------------
__global__ __launch_bounds__(256) void cvt_kernel(const float* __restrict__ in,
                                                  u16* __restrict__ out){
  int i = (blockIdx.x * 256 + threadIdx.x) * 4;
  float4 v = *(const float4*)(in + i);
  ushort4 o;
  o.x = f2b(v.x); o.y = f2b(v.y); o.z = f2b(v.z); o.w = f2b(v.w);
  *(ushort4*)(out + i) = o;
}

// ---------------- W [K][N] fp32 -> Wt [N][K] bf16 ----------------
__global__ __launch_bounds__(256) void transpose_w(const float* __restrict__ W,
                                                   u16* __restrict__ Wt,
                                                   int K, int N){
  __shared__ float tile[32][33];
  int bx = blockIdx.x;            // along N
  int by = blockIdx.y;            // along K
  int tx = threadIdx.x & 31, ty = threadIdx.x >> 5;   // 32 x 8
  int n = bx * 32 + tx;
  #pragma unroll
  for (int i = 0; i < 32; i += 8)
    tile[ty + i][tx] = W[(size_t)(by * 32 + ty + i) * N + n];
  __syncthreads();
  int k2 = by * 32 + tx;
  #pragma unroll
  for (int i = 0; i < 32; i += 8)
    Wt[(size_t)(bx * 32 + ty + i) * K + k2] = f2b(tile[tx][ty + i]);
}

// ---------------- MFMA GEMM: C[M,N] = A[M,K] @ Bt[N,K]^T, bf16 in ----------------
// m97 structure: 128x128 tile, BK=32, 4 waves (2x2 of 64x64), 16x16x32 bf16 MFMA,
// global_load_lds width=16 staging, conflict-free b128 fragment reads.
// MODE 0: bf16 C [M][N].  MODE 1: fp32 C [M][N].  MODE 2: KV scatter bf16 (Cp=kT, C2p=vB).
template<int MODE>
__global__ __launch_bounds__(256) void mgemm(const u16* __restrict__ A,
                                             const u16* __restrict__ Bt,
                                             void* __restrict__ Cp,
                                             u16* __restrict__ C2p,
                                             int M, int N, int K){
  __shared__ u16 As[128 * 32];    // [row][k] , row stride 32 elems = 64B
  __shared__ u16 Bs[128 * 32];    // [col][k]
  int tid = threadIdx.x;
  int wave = tid >> 6, lane = tid & 63;
  int m0 = blockIdx.x * 128, n0 = blockIdx.y * 128;
  int wm = (wave & 1) * 64, wn = (wave >> 1) * 64;
  int quad = lane >> 4, l16 = lane & 15;

  f32x4 acc[4][4];
  #pragma unroll
  for (int r = 0; r < 4; r++)
    #pragma unroll
    for (int c = 0; c < 4; c++) acc[r][c] = (f32x4){0.f, 0.f, 0.f, 0.f};

  // staging: wave stages rows [wave*32, wave*32+32) of both tiles.
  // lane l -> row wave*32 + c*16 + (l>>2), col seg (l&3)*8; LDS dst = base + l*16B.
  const u16* ag = A  + (size_t)(m0 + wave * 32 + (lane >> 2)) * K + (lane & 3) * 8;
  const u16* bg = Bt + (size_t)(n0 + wave * 32 + (lane >> 2)) * K + (lane & 3) * 8;
  u16* asl = As + wave * 32 * 32;
  u16* bsl = Bs + wave * 32 * 32;

  for (int k0 = 0; k0 < K; k0 += 32){
    GLDS16(ag + k0,            asl);
    GLDS16(ag + k0 + 16 * (size_t)K, asl + 16 * 32);
    GLDS16(bg + k0,            bsl);
    GLDS16(bg + k0 + 16 * (size_t)K, bsl + 16 * 32);
    __syncthreads();     // compiler drains vmcnt(0) before barrier -> staging visible
    bf16x8 af[4], bf[4];
    #pragma unroll
    for (int r = 0; r < 4; r++)
      af[r] = *(const bf16x8*)&As[(wm + r * 16 + l16) * 32 + quad * 8];
    #pragma unroll
    for (int c = 0; c < 4; c++)
      bf[c] = *(const bf16x8*)&Bs[(wn + c * 16 + l16) * 32 + quad * 8];
    #pragma unroll
    for (int r = 0; r < 4; r++)
      #pragma unroll
      for (int c = 0; c < 4; c++)
        acc[r][c] = __builtin_amdgcn_mfma_f32_16x16x32_bf16(af[r], bf[c], acc[r][c], 0, 0, 0);
    __syncthreads();     // all frag reads done before next stage overwrites
  }

  // epilogue: lane holds D[row = quad*4 + i][col = l16] per 16x16 tile
  #pragma unroll
  for (int r = 0; r < 4; r++){
    #pragma unroll
    for (int c = 0; c < 4; c++){
      int rG = m0 + wm + r * 16 + quad * 4;      // + i
      int cG = n0 + wn + c * 16 + l16;
      if (MODE == 0){
        u16* C = (u16*)Cp;
        #pragma unroll
        for (int i = 0; i < 4; i++)
          C[(size_t)(rG + i) * N + cG] = f2b(acc[r][c][i]);
      } else if (MODE == 1){
        float* C = (float*)Cp;
        #pragma unroll
        for (int i = 0; i < 4; i++)
          C[(size_t)(rG + i) * N + cG] = acc[r][c][i];
      } else {
        int bb = rG >> 11, jj = rG & 2047;       // rows of one tile never cross batch (4|2048)
        if (cG < INNER){
          int hh = cG >> 6, dd = cG & 63;
          u16* kp = (u16*)Cp + (((size_t)bb * HEADS + hh) * DHEAD + dd) * TM + jj;
          ushort4 o;
          o.x = f2b(acc[r][c][0]); o.y = f2b(acc[r][c][1]);
          o.z = f2b(acc[r][c][2]); o.w = f2b(acc[r][c][3]);
          *(ushort4*)kp = o;                     // jj consecutive -> 8B store
        } else {
          int cc = cG - INNER;
          int hh = cc >> 6, dd = cc & 63;
          u16* vp = C2p + (((size_t)bb * HEADS + hh) * TM + jj) * DHEAD + dd;
          #pragma unroll
          for (int i = 0; i < 4; i++)
            vp[(size_t)i * DHEAD] = f2b(acc[r][c][i]);
        }
      }
    }
  }
}

// ---------------- attention: 16 queries x 1 head per block, bf16 q/k/v ----------------
__global__ __launch_bounds__(256) void attn_kernel(const u16* __restrict__ qb,
                                                   const u16* __restrict__ kT,
                                                   const u16* __restrict__ vB,
                                                   const int* __restrict__ tt,
                                                   u16* __restrict__ ao){
  int t = threadIdx.x;
  int chunk = blockIdx.x & 127;
  int b = blockIdx.x >> 7;
  int h = blockIdx.y;
  int q0 = chunk * 16;
  __shared__ float qsT[64][16];
  __shared__ float Pb[16][256];
  __shared__ int miq[16];
  __shared__ int present[8];
  __shared__ float mxA[16], smA[16];
  if (t < 8) present[t] = 0;
  __syncthreads();
  if (t < 16){
    int v = tt[b * TTEXT + q0 + t] - 1;
    miq[t] = v;
    if (v >= 0 && v < 8) present[v] = 1;
  }
  for (int e = t; e < 1024; e += 256){
    int qq = e >> 6, dd = e & 63;
    qsT[dd][qq] = b2f(qb[(size_t)(b * TTEXT + q0 + qq) * INNER + h * DHEAD + dd]) * QSCALE;
  }
  __syncthreads();
  int j = t;
  int w = t >> 6, lane = t & 63;
  int d = t & 63, g = t >> 6;
  for (int mi = 0; mi < 8; mi++){
    if (!present[mi]) continue;          // uniform across block
    float s[16];
    #pragma unroll
    for (int q = 0; q < 16; q++) s[q] = 0.f;
    const u16* kp = kT + ((size_t)(b * HEADS + h) * DHEAD) * TM + mi * MTOK + j;
    for (int dd = 0; dd < 64; dd++){
      float kv = b2f(kp[(size_t)dd * TM]);
      const float4* qr = (const float4*)&qsT[dd][0];
      float4 qv0 = qr[0], qv1 = qr[1], qv2 = qr[2], qv3 = qr[3];
      s[0]  += qv0.x * kv; s[1]  += qv0.y * kv; s[2]  += qv0.z * kv; s[3]  += qv0.w * kv;
      s[4]  += qv1.x * kv; s[5]  += qv1.y * kv; s[6]  += qv1.z * kv; s[7]  += qv1.w * kv;
      s[8]  += qv2.x * kv; s[9]  += qv2.y * kv; s[10] += qv2.z * kv; s[11] += qv2.w * kv;
      s[12] += qv3.x * kv; s[13] += qv3.y * kv; s[14] += qv3.z * kv; s[15] += qv3.w * kv;
    }
    #pragma unroll
    for (int q = 0; q < 16; q++) Pb[q][j] = s[q];
    __syncthreads();
    #pragma unroll
    for (int qq = 0; qq < 4; qq++){
      int q = w * 4 + qq;
      float v0 = Pb[q][lane], v1 = Pb[q][lane+64], v2 = Pb[q][lane+128], v3 = Pb[q][lane+192];
      float m = fmaxf(fmaxf(v0, v1), fmaxf(v2, v3));
      #pragma unroll
      for (int off = 32; off; off >>= 1) m = fmaxf(m, __shfl_xor(m, off));
      float e = __expf(v0 - m) + __expf(v1 - m) + __expf(v2 - m) + __expf(v3 - m);
      #pragma unroll
      for (int off = 32; off; off >>= 1) e += __shfl_xor(e, off);
      if (lane == 0){ mxA[q] = m; smA[q] = 1.f / e; }
    }
    __syncthreads();
    #pragma unroll
    for (int q = 0; q < 16; q++) Pb[q][j] = __expf(s[q] - mxA[q]) * smA[q];
    __syncthreads();
    float o[4] = {0.f, 0.f, 0.f, 0.f};
    const u16* vp = vB + ((size_t)(b * HEADS + h) * TM + mi * MTOK) * DHEAD + d;
    for (int jj = 0; jj < 256; jj += 4){
      float vv0 = b2f(vp[(size_t)(jj + 0) * DHEAD]);
      float vv1 = b2f(vp[(size_t)(jj + 1) * DHEAD]);
      float vv2 = b2f(vp[(size_t)(jj + 2) * DHEAD]);
      float vv3 = b2f(vp[(size_t)(jj + 3) * DHEAD]);
      #pragma unroll
      for (int qq = 0; qq < 4; qq++){
        int q = g * 4 + qq;
        float4 p4 = *(const float4*)&Pb[q][jj];
        o[qq] += p4.x * vv0 + p4.y * vv1 + p4.z * vv2 + p4.w * vv3;
      }
    }
    #pragma unroll
    for (int qq = 0; qq < 4; qq++){
      int q = g * 4 + qq;
      if (miq[q] == mi)
        ao[(size_t)(b * TTEXT + q0 + q) * INNER + h * DHEAD + d] = f2b(o[qq]);
    }
    __syncthreads();
  }
  #pragma unroll
  for (int qq = 0; qq < 4; qq++){
    int q = g * 4 + qq;
    if (miq[q] < 0 || miq[q] > 7)
      ao[(size_t)(b * TTEXT + q0 + q) * INNER + h * DHEAD + d] = 0;
  }
}

extern "C" void kernel_launch(void* const* d_in, const int* in_sizes, int n_in,
                              void* d_out, int out_size, void* d_ws, size_t ws_size,
                              hipStream_t stream){
  const float* x      = (const float*)d_in[0];
  const float* media  = (const float*)d_in[1];
  const unsigned char* locs = (const unsigned char*)d_in[2];
  const float* gamma  = (const float*)d_in[3];
  const float* beta   = (const float*)d_in[4];
  const float* Wq     = (const float*)d_in[5];
  const float* Wkv    = (const float*)d_in[6];
  const float* Wout   = (const float*)d_in[7];

  // workspace layout (~58 MB), all bf16 intermediates
  char* ws = (char*)d_ws;
  int* tt    = (int*)ws;   ws += 16384;
  u16* xn    = (u16*)ws;   ws += (size_t)4096 * 1024 * 2;   // [B*T][DIM]
  u16* medb  = (u16*)ws;   ws += (size_t)4096 * 1024 * 2;   // [B*TM][DIM]
  u16* Wqt   = (u16*)ws;   ws += (size_t)1024 * 1024 * 2;   // [INNER][DIM]
  u16* Wkvt  = (u16*)ws;   ws += (size_t)2048 * 1024 * 2;   // [2*INNER][DIM]
  u16* Woutt = (u16*)ws;   ws += (size_t)1024 * 1024 * 2;   // [DIM][INNER]
  u16* qb    = (u16*)ws;   ws += (size_t)4096 * 1024 * 2;   // [B*T][INNER]
  u16* kT    = (u16*)ws;   ws += (size_t)4096 * 1024 * 2;   // [B,H,64,TM]
  u16* vB    = (u16*)ws;   ws += (size_t)4096 * 1024 * 2;   // [B,H,TM,64]
  u16* ao    = (u16*)ws;   ws += (size_t)4096 * 1024 * 2;   // [B*T][INNER]

  scan_kernel<<<1, 256, 0, stream>>>(locs, tt);
  ln_kernel<<<BATCH * TTEXT, 256, 0, stream>>>(x, gamma, beta, xn);
  cvt_kernel<<<4096, 256, 0, stream>>>(media, medb);
  transpose_w<<<dim3(32, 32), 256, 0, stream>>>(Wq,   Wqt,   1024, 1024);
  transpose_w<<<dim3(64, 32), 256, 0, stream>>>(Wkv,  Wkvt,  1024, 2048);
  transpose_w<<<dim3(32, 32), 256, 0, stream>>>(Wout, Woutt, 1024, 1024);
  mgemm<0><<<dim3(32, 8),  256, 0, stream>>>(xn,   Wqt,   qb,    nullptr, 4096, 1024, 1024);
  mgemm<2><<<dim3(32, 16), 256, 0, stream>>>(medb, Wkvt,  kT,    vB,      4096, 2048, 1024);
  attn_kernel<<<dim3(256, 16), 256, 0, stream>>>(qb, kT, vB, tt, ao);
  mgemm<1><<<dim3(32, 8),  256, 0, stream>>>(ao,   Woutt, d_out, nullptr, 4096, 1024, 1024);
}

// Round 6
// 238.508 us; speedup vs baseline: 3.1152x; 1.4264x over previous
//
#include <hip/hip_runtime.h>

typedef unsigned short u16;
typedef unsigned int u32;

#define BATCH 2
#define TTEXT 2048
#define DIM 1024
#define TMED 8
#define MTOK 256
#define HEADS 16
#define DHEAD 64
#define INNER 1024
#define TM 2048            // TMED * MTOK
#define QSCALE 0.125f      // DHEAD^-0.5
#define QCHUNK 64          // queries per attention block

typedef __attribute__((ext_vector_type(8))) short bf16x8;
typedef __attribute__((ext_vector_type(4))) float f32x4;

__device__ __forceinline__ float b2f(u16 u){
  union { float f; u32 i; } x; x.i = ((u32)u) << 16; return x.f;
}
__device__ __forceinline__ u16 f2b(float f){
  union { float f; u32 i; } x; x.f = f;
  u32 r = x.i + 0x7FFFu + ((x.i >> 16) & 1u);   // RNE
  return (u16)(r >> 16);
}

#define GLDS16(g, l) __builtin_amdgcn_global_load_lds( \
    (const __attribute__((address_space(1))) u32*)(g), \
    (__attribute__((address_space(3))) u32*)(l), 16, 0, 0)

// ---------------- text_time = cumsum(media_locations) ----------------
__global__ __launch_bounds__(256) void scan_kernel(const unsigned char* __restrict__ raw,
                                                   int* __restrict__ tt){
  int t = threadIdx.x;
  __shared__ int sd[256];
  int c = 0;
  for (int i = t; i < 4096; i += 256) c += (raw[i] != 0);
  sd[t] = c; __syncthreads();
  for (int off = 128; off; off >>= 1){
    if (t < off) sd[t] += sd[t + off];
    __syncthreads();
  }
  int is_byte = (sd[0] >= 9);
  __syncthreads();
  const int* as_int = (const int*)raw;
  for (int b = 0; b < BATCH; b++){
    int inc[8]; int s = 0;
    #pragma unroll
    for (int k = 0; k < 8; k++){
      int i = b * TTEXT + t * 8 + k;
      int v = is_byte ? (raw[i] != 0) : (as_int[i] != 0);
      s += v; inc[k] = s;
    }
    sd[t] = s; __syncthreads();
    for (int off = 1; off < 256; off <<= 1){
      int v = (t >= off) ? sd[t - off] : 0;
      __syncthreads();
      sd[t] += v;
      __syncthreads();
    }
    int excl = sd[t] - s;
    #pragma unroll
    for (int k = 0; k < 8; k++) tt[b * TTEXT + t * 8 + k] = excl + inc[k];
    __syncthreads();
  }
}

// ---------------- LayerNorm: x(fp32) -> xn(bf16) ----------------
__global__ __launch_bounds__(256) void ln_kernel(const float* __restrict__ x,
                                                 const float* __restrict__ gamma,
                                                 const float* __restrict__ beta,
                                                 u16* __restrict__ xn){
  int row = blockIdx.x, t = threadIdx.x;
  float4 v = *(const float4*)(x + (size_t)row * DIM + t * 4);
  float s  = v.x + v.y + v.z + v.w;
  float ss = v.x*v.x + v.y*v.y + v.z*v.z + v.w*v.w;
  #pragma unroll
  for (int off = 32; off; off >>= 1){ s += __shfl_xor(s, off); ss += __shfl_xor(ss, off); }
  __shared__ float ps[4], pss[4];
  __shared__ float mu_s, rs_s;
  int w = t >> 6;
  if ((t & 63) == 0){ ps[w] = s; pss[w] = ss; }
  __syncthreads();
  if (t == 0){
    float S = ps[0] + ps[1] + ps[2] + ps[3];
    float SS = pss[0] + pss[1] + pss[2] + pss[3];
    float mu = S * (1.f / DIM);
    float var = SS * (1.f / DIM) - mu * mu;
    mu_s = mu; rs_s = rsqrtf(var + 1e-5f);
  }
  __syncthreads();
  float mu = mu_s, rs = rs_s;
  float4 g  = *(const float4*)(gamma + t * 4);
  float4 be = *(const float4*)(beta + t * 4);
  ushort4 o;
  o.x = f2b((v.x - mu) * rs * g.x + be.x);
  o.y = f2b((v.y - mu) * rs * g.y + be.y);
  o.z = f2b((v.z - mu) * rs * g.z + be.z);
  o.w = f2b((v.w - mu) * rs * g.w + be.w);
  *(ushort4*)(xn + (size_t)row * DIM + t * 4) = o;
}

// ---------------- fp32 -> bf16 elementwise (media) ----------------
__global__ __launch_bounds__(256) void cvt_kernel(const float* __restrict__ in,
                                                  u16* __restrict__ out){
  int i = (blockIdx.x * 256 + threadIdx.x) * 4;
  float4 v = *(const float4*)(in + i);
  ushort4 o;
  o.x = f2b(v.x); o.y = f2b(v.y); o.z = f2b(v.z); o.w = f2b(v.w);
  *(ushort4*)(out + i) = o;
}

// ---------------- W [K][N] fp32 -> Wt [N][K] bf16 ----------------
__global__ __launch_bounds__(256) void transpose_w(const float* __restrict__ W,
                                                   u16* __restrict__ Wt,
                                                   int K, int N){
  __shared__ float tile[32][33];
  int bx = blockIdx.x;            // along N
  int by = blockIdx.y;            // along K
  int tx = threadIdx.x & 31, ty = threadIdx.x >> 5;   // 32 x 8
  int n = bx * 32 + tx;
  #pragma unroll
  for (int i = 0; i < 32; i += 8)
    tile[ty + i][tx] = W[(size_t)(by * 32 + ty + i) * N + n];
  __syncthreads();
  int k2 = by * 32 + tx;
  #pragma unroll
  for (int i = 0; i < 32; i += 8)
    Wt[(size_t)(bx * 32 + ty + i) * K + k2] = f2b(tile[tx][ty + i]);
}

// ---------------- MFMA GEMM: C[M,N] = A[M,K] @ Bt[N,K]^T, bf16 in ----------------
// MODE 0: bf16 C [M][N].  MODE 1: fp32 C [M][N].
// MODE 2: KV scatter bf16 -> K token-major [B,H,TM,64] (Cp), V dim-major [B,H,64,TM] (C2p).
template<int MODE>
__global__ __launch_bounds__(256) void mgemm(const u16* __restrict__ A,
                                             const u16* __restrict__ Bt,
                                             void* __restrict__ Cp,
                                             u16* __restrict__ C2p,
                                             int M, int N, int K){
  __shared__ u16 As[128 * 32];    // [row][k], row stride 32 elems = 64B
  __shared__ u16 Bs[128 * 32];    // [col][k]
  int tid = threadIdx.x;
  int wave = tid >> 6, lane = tid & 63;
  int m0 = blockIdx.x * 128, n0 = blockIdx.y * 128;
  int wm = (wave & 1) * 64, wn = (wave >> 1) * 64;
  int quad = lane >> 4, l16 = lane & 15;

  f32x4 acc[4][4];
  #pragma unroll
  for (int r = 0; r < 4; r++)
    #pragma unroll
    for (int c = 0; c < 4; c++) acc[r][c] = (f32x4){0.f, 0.f, 0.f, 0.f};

  const u16* ag = A  + (size_t)(m0 + wave * 32 + (lane >> 2)) * K + (lane & 3) * 8;
  const u16* bg = Bt + (size_t)(n0 + wave * 32 + (lane >> 2)) * K + (lane & 3) * 8;
  u16* asl = As + wave * 32 * 32;
  u16* bsl = Bs + wave * 32 * 32;

  for (int k0 = 0; k0 < K; k0 += 32){
    GLDS16(ag + k0,                  asl);
    GLDS16(ag + k0 + 16 * (size_t)K, asl + 16 * 32);
    GLDS16(bg + k0,                  bsl);
    GLDS16(bg + k0 + 16 * (size_t)K, bsl + 16 * 32);
    __syncthreads();
    bf16x8 af[4], bf[4];
    #pragma unroll
    for (int r = 0; r < 4; r++)
      af[r] = *(const bf16x8*)&As[(wm + r * 16 + l16) * 32 + quad * 8];
    #pragma unroll
    for (int c = 0; c < 4; c++)
      bf[c] = *(const bf16x8*)&Bs[(wn + c * 16 + l16) * 32 + quad * 8];
    #pragma unroll
    for (int r = 0; r < 4; r++)
      #pragma unroll
      for (int c = 0; c < 4; c++)
        acc[r][c] = __builtin_amdgcn_mfma_f32_16x16x32_bf16(af[r], bf[c], acc[r][c], 0, 0, 0);
    __syncthreads();
  }

  #pragma unroll
  for (int r = 0; r < 4; r++){
    #pragma unroll
    for (int c = 0; c < 4; c++){
      int rG = m0 + wm + r * 16 + quad * 4;      // + i
      int cG = n0 + wn + c * 16 + l16;
      if (MODE == 0){
        u16* C = (u16*)Cp;
        #pragma unroll
        for (int i = 0; i < 4; i++)
          C[(size_t)(rG + i) * N + cG] = f2b(acc[r][c][i]);
      } else if (MODE == 1){
        float* C = (float*)Cp;
        #pragma unroll
        for (int i = 0; i < 4; i++)
          C[(size_t)(rG + i) * N + cG] = acc[r][c][i];
      } else {
        int bb = rG >> 11, jj = rG & 2047;       // 4-row groups never cross batch
        if (cG < INNER){
          // K token-major: kB[((b*H+h)*TM + token)*64 + d]
          int hh = cG >> 6, dd = cG & 63;
          u16* kp = (u16*)Cp + (((size_t)bb * HEADS + hh) * TM + jj) * DHEAD + dd;
          #pragma unroll
          for (int i = 0; i < 4; i++)
            kp[(size_t)i * DHEAD] = f2b(acc[r][c][i]);
        } else {
          // V dim-major: vT[((b*H+h)*64 + d)*TM + token]
          int cc = cG - INNER;
          int hh = cc >> 6, dd = cc & 63;
          u16* vp = C2p + (((size_t)bb * HEADS + hh) * DHEAD + dd) * TM + jj;
          ushort4 o;
          o.x = f2b(acc[r][c][0]); o.y = f2b(acc[r][c][1]);
          o.z = f2b(acc[r][c][2]); o.w = f2b(acc[r][c][3]);
          *(ushort4*)vp = o;
        }
      }
    }
  }
}

// ---------------- MFMA attention: 64 queries x 1 head per block ----------------
// Wave w owns query rows [w*16, w*16+16): QK^T via mfma (S in regs, C-layout),
// softmax via 16-lane shuffles, P -> LDS (A-layout, bf16), PV via mfma.
// K staged token-major in 128-key halves; P reuses the K LDS region.
__global__ __launch_bounds__(256) void attn_kernel(const u16* __restrict__ qb,
                                                   const u16* __restrict__ kB,
                                                   const u16* __restrict__ vT,
                                                   const int* __restrict__ tt,
                                                   u16* __restrict__ ao){
  __shared__ u16 Qs[64 * 72];          // [q][d], pad 64->72
  __shared__ u16 KsP[128 * 72];        // K half [128 keys][72]; reused as P half [64 q][136]
  __shared__ u16 Vt[64 * 264];         // [d][key], pad 256->264
  __shared__ int miq[QCHUNK];
  __shared__ int present[8];

  int t = threadIdx.x;
  int wave = t >> 6, lane = t & 63, quad = lane >> 4, l16 = lane & 15;
  int chunk = blockIdx.x & 31;         // TTEXT/QCHUNK = 32
  int b = blockIdx.x >> 5;
  int h = blockIdx.y;
  int q0 = chunk * QCHUNK;

  if (t < 8) present[t] = 0;
  __syncthreads();
  if (t < QCHUNK){
    int v = tt[b * TTEXT + q0 + t] - 1;
    miq[t] = v;
    if (v >= 0 && v < 8) present[v] = 1;
  }
  // stage Q: 64 rows x 8 segs of 8 elems
  #pragma unroll
  for (int p = 0; p < 2; p++){
    int idx = p * 256 + t;
    int row = idx >> 3, seg = idx & 7;
    uint4 v = *(const uint4*)(qb + (size_t)(b * TTEXT + q0 + row) * INNER + h * DHEAD + seg * 8);
    *(uint4*)(Qs + row * 72 + seg * 8) = v;
  }
  __syncthreads();

  const size_t kvh = (size_t)b * HEADS + h;
  const u16* kg = kB + kvh * TM * DHEAD;            // [token][64]
  const u16* vg = vT + kvh * DHEAD * TM;            // [d][TM]

  for (int mi = 0; mi < 8; mi++){
    if (!present[mi]) continue;                     // block-uniform

    // stage Vt [64][256] -> [64][264]
    #pragma unroll
    for (int p = 0; p < 8; p++){
      int idx = p * 256 + t;
      int row = idx >> 5, seg = idx & 31;
      uint4 v = *(const uint4*)(vg + (size_t)row * TM + mi * MTOK + seg * 8);
      *(uint4*)(Vt + row * 264 + seg * 8) = v;
    }

    f32x4 S[16];
    #pragma unroll
    for (int c = 0; c < 16; c++) S[c] = (f32x4){0.f, 0.f, 0.f, 0.f};

    // QK^T over two 128-key halves staged into KsP
    #pragma unroll
    for (int kh = 0; kh < 2; kh++){
      __syncthreads();   // prior reads of KsP done (prev half / prev mi P)
      #pragma unroll
      for (int p = 0; p < 4; p++){
        int idx = p * 256 + t;
        int row = idx >> 3, seg = idx & 7;
        uint4 v = *(const uint4*)(kg + (size_t)(mi * MTOK + kh * 128 + row) * DHEAD + seg * 8);
        *(uint4*)(KsP + row * 72 + seg * 8) = v;
      }
      __syncthreads();
      #pragma unroll
      for (int ks = 0; ks < 2; ks++){
        bf16x8 aq = *(const bf16x8*)&Qs[(wave * 16 + l16) * 72 + ks * 32 + quad * 8];
        #pragma unroll
        for (int c = 0; c < 8; c++){
          bf16x8 bk = *(const bf16x8*)&KsP[(c * 16 + l16) * 72 + ks * 32 + quad * 8];
          S[kh * 8 + c] = __builtin_amdgcn_mfma_f32_16x16x32_bf16(aq, bk, S[kh * 8 + c], 0, 0, 0);
        }
      }
    }

    // softmax in regs; lane holds S[row=quad*4+i][key=c*16+l16]
    float mx[4], sm[4];
    #pragma unroll
    for (int i = 0; i < 4; i++) mx[i] = -1e30f;
    #pragma unroll
    for (int c = 0; c < 16; c++)
      #pragma unroll
      for (int i = 0; i < 4; i++){
        float sv = S[c][i] * QSCALE; S[c][i] = sv; mx[i] = fmaxf(mx[i], sv);
      }
    #pragma unroll
    for (int off = 1; off < 16; off <<= 1)
      #pragma unroll
      for (int i = 0; i < 4; i++) mx[i] = fmaxf(mx[i], __shfl_xor(mx[i], off));
    #pragma unroll
    for (int i = 0; i < 4; i++) sm[i] = 0.f;
    #pragma unroll
    for (int c = 0; c < 16; c++)
      #pragma unroll
      for (int i = 0; i < 4; i++){
        float e = __expf(S[c][i] - mx[i]); S[c][i] = e; sm[i] += e;
      }
    #pragma unroll
    for (int off = 1; off < 16; off <<= 1)
      #pragma unroll
      for (int i = 0; i < 4; i++) sm[i] += __shfl_xor(sm[i], off);
    #pragma unroll
    for (int i = 0; i < 4; i++) sm[i] = 1.f / sm[i];

    // PV over two key halves; P half written into KsP region (A-layout)
    f32x4 O[4];
    #pragma unroll
    for (int c4 = 0; c4 < 4; c4++) O[c4] = (f32x4){0.f, 0.f, 0.f, 0.f};
    #pragma unroll
    for (int kh = 0; kh < 2; kh++){
      __syncthreads();   // KsP reads (QK / prev P) done
      #pragma unroll
      for (int c = 0; c < 8; c++)
        #pragma unroll
        for (int i = 0; i < 4; i++)
          KsP[(wave * 16 + quad * 4 + i) * 136 + c * 16 + l16] = f2b(S[kh * 8 + c][i] * sm[i]);
      __syncthreads();
      #pragma unroll
      for (int k0 = 0; k0 < 4; k0++){
        bf16x8 ap = *(const bf16x8*)&KsP[(wave * 16 + l16) * 136 + k0 * 32 + quad * 8];
        #pragma unroll
        for (int c4 = 0; c4 < 4; c4++){
          bf16x8 bv = *(const bf16x8*)&Vt[(c4 * 16 + l16) * 264 + kh * 128 + k0 * 32 + quad * 8];
          O[c4] = __builtin_amdgcn_mfma_f32_16x16x32_bf16(ap, bv, O[c4], 0, 0, 0);
        }
      }
    }

    // write O for queries assigned to this media block
    #pragma unroll
    for (int c4 = 0; c4 < 4; c4++)
      #pragma unroll
      for (int i = 0; i < 4; i++){
        int q = wave * 16 + quad * 4 + i;
        if (miq[q] == mi)
          ao[(size_t)(b * TTEXT + q0 + q) * INNER + h * DHEAD + c4 * 16 + l16] = f2b(O[c4][i]);
      }
    __syncthreads();   // before next mi restages Vt/KsP
  }

  // zero rows with no media
  #pragma unroll
  for (int p = 0; p < 16; p++){
    int idx = p * 256 + t;
    int q = idx >> 6, dd = idx & 63;
    if (miq[q] < 0 || miq[q] > 7)
      ao[(size_t)(b * TTEXT + q0 + q) * INNER + h * DHEAD + dd] = 0;
  }
}

extern "C" void kernel_launch(void* const* d_in, const int* in_sizes, int n_in,
                              void* d_out, int out_size, void* d_ws, size_t ws_size,
                              hipStream_t stream){
  const float* x      = (const float*)d_in[0];
  const float* media  = (const float*)d_in[1];
  const unsigned char* locs = (const unsigned char*)d_in[2];
  const float* gamma  = (const float*)d_in[3];
  const float* beta   = (const float*)d_in[4];
  const float* Wq     = (const float*)d_in[5];
  const float* Wkv    = (const float*)d_in[6];
  const float* Wout   = (const float*)d_in[7];

  // workspace layout (~58 MB), all bf16 intermediates
  char* ws = (char*)d_ws;
  int* tt    = (int*)ws;   ws += 16384;
  u16* xn    = (u16*)ws;   ws += (size_t)4096 * 1024 * 2;   // [B*T][DIM]
  u16* medb  = (u16*)ws;   ws += (size_t)4096 * 1024 * 2;   // [B*TM][DIM]
  u16* Wqt   = (u16*)ws;   ws += (size_t)1024 * 1024 * 2;   // [INNER][DIM]
  u16* Wkvt  = (u16*)ws;   ws += (size_t)2048 * 1024 * 2;   // [2*INNER][DIM]
  u16* Woutt = (u16*)ws;   ws += (size_t)1024 * 1024 * 2;   // [DIM][INNER]
  u16* qb    = (u16*)ws;   ws += (size_t)4096 * 1024 * 2;   // [B*T][INNER]
  u16* kB    = (u16*)ws;   ws += (size_t)4096 * 1024 * 2;   // [B,H,TM,64] token-major
  u16* vT    = (u16*)ws;   ws += (size_t)4096 * 1024 * 2;   // [B,H,64,TM] dim-major
  u16* ao    = (u16*)ws;   ws += (size_t)4096 * 1024 * 2;   // [B*T][INNER]

  scan_kernel<<<1, 256, 0, stream>>>(locs, tt);
  ln_kernel<<<BATCH * TTEXT, 256, 0, stream>>>(x, gamma, beta, xn);
  cvt_kernel<<<4096, 256, 0, stream>>>(media, medb);
  transpose_w<<<dim3(32, 32), 256, 0, stream>>>(Wq,   Wqt,   1024, 1024);
  transpose_w<<<dim3(64, 32), 256, 0, stream>>>(Wkv,  Wkvt,  1024, 2048);
  transpose_w<<<dim3(32, 32), 256, 0, stream>>>(Wout, Woutt, 1024, 1024);
  mgemm<0><<<dim3(32, 8),  256, 0, stream>>>(xn,   Wqt,   qb,    nullptr, 4096, 1024, 1024);
  mgemm<2><<<dim3(32, 16), 256, 0, stream>>>(medb, Wkvt,  kB,    vT,      4096, 2048, 1024);
  attn_kernel<<<dim3(64, 16), 256, 0, stream>>>(qb, kB, vT, tt, ao);
  mgemm<1><<<dim3(32, 8),  256, 0, stream>>>(ao,   Woutt, d_out, nullptr, 4096, 1024, 1024);
}

// Round 8
// 236.402 us; speedup vs baseline: 3.1430x; 1.0089x over previous
//
#include <hip/hip_runtime.h>

typedef unsigned short u16;
typedef unsigned int u32;

#define BATCH 2
#define TTEXT 2048
#define DIM 1024
#define TMED 8
#define MTOK 256
#define HEADS 16
#define DHEAD 64
#define INNER 1024
#define TM 2048            // TMED * MTOK
#define QSCALE 0.125f      // DHEAD^-0.5
#define QCHUNK 64          // queries per attention block

typedef __attribute__((ext_vector_type(8))) short bf16x8;
typedef __attribute__((ext_vector_type(4))) float f32x4;

__device__ __forceinline__ float b2f(u16 u){
  union { float f; u32 i; } x; x.i = ((u32)u) << 16; return x.f;
}
__device__ __forceinline__ u16 f2b(float f){
  union { float f; u32 i; } x; x.f = f;
  u32 r = x.i + 0x7FFFu + ((x.i >> 16) & 1u);   // RNE
  return (u16)(r >> 16);
}

#define GLDS16(g, l) __builtin_amdgcn_global_load_lds( \
    (const __attribute__((address_space(1))) u32*)(g), \
    (__attribute__((address_space(3))) u32*)(l), 16, 0, 0)

// ---------------- text_time = cumsum(media_locations) ----------------
__global__ __launch_bounds__(256) void scan_kernel(const unsigned char* __restrict__ raw,
                                                   int* __restrict__ tt){
  int t = threadIdx.x;
  __shared__ int sd[256];
  int c = 0;
  for (int i = t; i < 4096; i += 256) c += (raw[i] != 0);
  sd[t] = c; __syncthreads();
  for (int off = 128; off; off >>= 1){
    if (t < off) sd[t] += sd[t + off];
    __syncthreads();
  }
  int is_byte = (sd[0] >= 9);
  __syncthreads();
  const int* as_int = (const int*)raw;
  for (int b = 0; b < BATCH; b++){
    int inc[8]; int s = 0;
    #pragma unroll
    for (int k = 0; k < 8; k++){
      int i = b * TTEXT + t * 8 + k;
      int v = is_byte ? (raw[i] != 0) : (as_int[i] != 0);
      s += v; inc[k] = s;
    }
    sd[t] = s; __syncthreads();
    for (int off = 1; off < 256; off <<= 1){
      int v = (t >= off) ? sd[t - off] : 0;
      __syncthreads();
      sd[t] += v;
      __syncthreads();
    }
    int excl = sd[t] - s;
    #pragma unroll
    for (int k = 0; k < 8; k++) tt[b * TTEXT + t * 8 + k] = excl + inc[k];
    __syncthreads();
  }
}

// ---------------- LayerNorm: x(fp32) -> xn(bf16) ----------------
__global__ __launch_bounds__(256) void ln_kernel(const float* __restrict__ x,
                                                 const float* __restrict__ gamma,
                                                 const float* __restrict__ beta,
                                                 u16* __restrict__ xn){
  int row = blockIdx.x, t = threadIdx.x;
  float4 v = *(const float4*)(x + (size_t)row * DIM + t * 4);
  float s  = v.x + v.y + v.z + v.w;
  float ss = v.x*v.x + v.y*v.y + v.z*v.z + v.w*v.w;
  #pragma unroll
  for (int off = 32; off; off >>= 1){ s += __shfl_xor(s, off); ss += __shfl_xor(ss, off); }
  __shared__ float ps[4], pss[4];
  __shared__ float mu_s, rs_s;
  int w = t >> 6;
  if ((t & 63) == 0){ ps[w] = s; pss[w] = ss; }
  __syncthreads();
  if (t == 0){
    float S = ps[0] + ps[1] + ps[2] + ps[3];
    float SS = pss[0] + pss[1] + pss[2] + pss[3];
    float mu = S * (1.f / DIM);
    float var = SS * (1.f / DIM) - mu * mu;
    mu_s = mu; rs_s = rsqrtf(var + 1e-5f);
  }
  __syncthreads();
  float mu = mu_s, rs = rs_s;
  float4 g  = *(const float4*)(gamma + t * 4);
  float4 be = *(const float4*)(beta + t * 4);
  ushort4 o;
  o.x = f2b((v.x - mu) * rs * g.x + be.x);
  o.y = f2b((v.y - mu) * rs * g.y + be.y);
  o.z = f2b((v.z - mu) * rs * g.z + be.z);
  o.w = f2b((v.w - mu) * rs * g.w + be.w);
  *(ushort4*)(xn + (size_t)row * DIM + t * 4) = o;
}

// ---------------- fp32 -> bf16 elementwise (media) ----------------
__global__ __launch_bounds__(256) void cvt_kernel(const float* __restrict__ in,
                                                  u16* __restrict__ out){
  int i = (blockIdx.x * 256 + threadIdx.x) * 4;
  float4 v = *(const float4*)(in + i);
  ushort4 o;
  o.x = f2b(v.x); o.y = f2b(v.y); o.z = f2b(v.z); o.w = f2b(v.w);
  *(ushort4*)(out + i) = o;
}

// ---------------- W [K][N] fp32 -> Wt [N][K] bf16 ----------------
__global__ __launch_bounds__(256) void transpose_w(const float* __restrict__ W,
                                                   u16* __restrict__ Wt,
                                                   int K, int N){
  __shared__ float tile[32][33];
  int bx = blockIdx.x;            // along N
  int by = blockIdx.y;            // along K
  int tx = threadIdx.x & 31, ty = threadIdx.x >> 5;   // 32 x 8
  int n = bx * 32 + tx;
  #pragma unroll
  for (int i = 0; i < 32; i += 8)
    tile[ty + i][tx] = W[(size_t)(by * 32 + ty + i) * N + n];
  __syncthreads();
  int k2 = by * 32 + tx;
  #pragma unroll
  for (int i = 0; i < 32; i += 8)
    Wt[(size_t)(bx * 32 + ty + i) * K + k2] = f2b(tile[tx][ty + i]);
}

// ---------------- MFMA GEMM: C[M,N] = A[M,K] @ Bt[N,K]^T, bf16 in ----------------
// MODE 0: bf16 C [M][N].  MODE 1: fp32 C [M][N].
// MODE 2: KV scatter bf16 -> K token-major [B,H,TM,64] (Cp), V dim-major [B,H,64,TM] (C2p).
template<int MODE>
__global__ __launch_bounds__(256) void mgemm(const u16* __restrict__ A,
                                             const u16* __restrict__ Bt,
                                             void* __restrict__ Cp,
                                             u16* __restrict__ C2p,
                                             int M, int N, int K){
  __shared__ u16 As[128 * 32];    // [row][k], row stride 32 elems = 64B
  __shared__ u16 Bs[128 * 32];    // [col][k]
  int tid = threadIdx.x;
  int wave = tid >> 6, lane = tid & 63;
  int m0 = blockIdx.x * 128, n0 = blockIdx.y * 128;
  int wm = (wave & 1) * 64, wn = (wave >> 1) * 64;
  int quad = lane >> 4, l16 = lane & 15;

  f32x4 acc[4][4];
  #pragma unroll
  for (int r = 0; r < 4; r++)
    #pragma unroll
    for (int c = 0; c < 4; c++) acc[r][c] = (f32x4){0.f, 0.f, 0.f, 0.f};

  const u16* ag = A  + (size_t)(m0 + wave * 32 + (lane >> 2)) * K + (lane & 3) * 8;
  const u16* bg = Bt + (size_t)(n0 + wave * 32 + (lane >> 2)) * K + (lane & 3) * 8;
  u16* asl = As + wave * 32 * 32;
  u16* bsl = Bs + wave * 32 * 32;

  for (int k0 = 0; k0 < K; k0 += 32){
    GLDS16(ag + k0,                  asl);
    GLDS16(ag + k0 + 16 * (size_t)K, asl + 16 * 32);
    GLDS16(bg + k0,                  bsl);
    GLDS16(bg + k0 + 16 * (size_t)K, bsl + 16 * 32);
    __syncthreads();
    bf16x8 af[4], bf[4];
    #pragma unroll
    for (int r = 0; r < 4; r++)
      af[r] = *(const bf16x8*)&As[(wm + r * 16 + l16) * 32 + quad * 8];
    #pragma unroll
    for (int c = 0; c < 4; c++)
      bf[c] = *(const bf16x8*)&Bs[(wn + c * 16 + l16) * 32 + quad * 8];
    #pragma unroll
    for (int r = 0; r < 4; r++)
      #pragma unroll
      for (int c = 0; c < 4; c++)
        acc[r][c] = __builtin_amdgcn_mfma_f32_16x16x32_bf16(af[r], bf[c], acc[r][c], 0, 0, 0);
    __syncthreads();
  }

  #pragma unroll
  for (int r = 0; r < 4; r++){
    #pragma unroll
    for (int c = 0; c < 4; c++){
      int rG = m0 + wm + r * 16 + quad * 4;      // + i
      int cG = n0 + wn + c * 16 + l16;
      if (MODE == 0){
        u16* C = (u16*)Cp;
        #pragma unroll
        for (int i = 0; i < 4; i++)
          C[(size_t)(rG + i) * N + cG] = f2b(acc[r][c][i]);
      } else if (MODE == 1){
        float* C = (float*)Cp;
        #pragma unroll
        for (int i = 0; i < 4; i++)
          C[(size_t)(rG + i) * N + cG] = acc[r][c][i];
      } else {
        int bb = rG >> 11, jj = rG & 2047;       // 4-row groups never cross batch
        if (cG < INNER){
          // K token-major: kB[((b*H+h)*TM + token)*64 + d]
          int hh = cG >> 6, dd = cG & 63;
          u16* kp = (u16*)Cp + (((size_t)bb * HEADS + hh) * TM + jj) * DHEAD + dd;
          #pragma unroll
          for (int i = 0; i < 4; i++)
            kp[(size_t)i * DHEAD] = f2b(acc[r][c][i]);
        } else {
          // V dim-major: vT[((b*H+h)*64 + d)*TM + token]
          int cc = cG - INNER;
          int hh = cc >> 6, dd = cc & 63;
          u16* vp = C2p + (((size_t)bb * HEADS + hh) * DHEAD + dd) * TM + jj;
          ushort4 o;
          o.x = f2b(acc[r][c][0]); o.y = f2b(acc[r][c][1]);
          o.z = f2b(acc[r][c][2]); o.w = f2b(acc[r][c][3]);
          *(ushort4*)vp = o;
        }
      }
    }
  }
}

// ---------------- MFMA attention: 64 queries x 1 head per block ----------------
// Round-6 proven structure (K and V staged via LDS with double-barrier pattern)
// with two safe deltas: (1) Q fragments direct from global (per-wave private,
// no LDS interaction); (2) V staged per-128-key half (Vh) inside the PV loop.
// LDS ~36 KB -> 4 blocks/CU (entire grid co-resident).
__global__ __launch_bounds__(256, 4) void attn_kernel(const u16* __restrict__ qb,
                                                      const u16* __restrict__ kB,
                                                      const u16* __restrict__ vT,
                                                      const int* __restrict__ tt,
                                                      u16* __restrict__ ao){
  __shared__ u16 KsP[128 * 72];        // K half [128 keys][72]; reused as P half [64 q][136]
  __shared__ u16 Vh[64 * 136];         // V half [64 d][128 keys pad->136]
  __shared__ int miq[QCHUNK];
  __shared__ int present[8];

  int t = threadIdx.x;
  int wave = t >> 6, lane = t & 63, quad = lane >> 4, l16 = lane & 15;
  int chunk = blockIdx.x & 31;         // TTEXT/QCHUNK = 32
  int b = blockIdx.x >> 5;
  int h = blockIdx.y;
  int q0 = chunk * QCHUNK;

  if (t < 8) present[t] = 0;
  __syncthreads();
  if (t < QCHUNK){
    int v = tt[b * TTEXT + q0 + t] - 1;
    miq[t] = v;
    if (v >= 0 && v < 8) present[v] = 1;
  }
  // Q fragments direct from global: q row = wave*16 + l16, d = ks*32 + quad*8
  const u16* qrow = qb + (size_t)(b * TTEXT + q0 + wave * 16 + l16) * INNER
                       + h * DHEAD + quad * 8;
  bf16x8 aq0 = *(const bf16x8*)(qrow);
  bf16x8 aq1 = *(const bf16x8*)(qrow + 32);
  __syncthreads();                     // miq/present visible to all

  const size_t kvh = (size_t)b * HEADS + h;
  const u16* kg = kB + kvh * TM * DHEAD;            // [token][64]
  const u16* vg = vT + kvh * DHEAD * TM;            // [d][TM]

  for (int mi = 0; mi < 8; mi++){
    if (!present[mi]) continue;                     // block-uniform

    // ---- QK^T over two 128-key halves staged into KsP ----
    f32x4 S[16];
    #pragma unroll
    for (int c = 0; c < 16; c++) S[c] = (f32x4){0.f, 0.f, 0.f, 0.f};
    #pragma unroll
    for (int kh = 0; kh < 2; kh++){
      __syncthreads();   // prior KsP reads done (prev half QK / prev mi P)
      #pragma unroll
      for (int p = 0; p < 4; p++){
        int idx = p * 256 + t;
        int row = idx >> 3, seg = idx & 7;
        uint4 v = *(const uint4*)(kg + (size_t)(mi * MTOK + kh * 128 + row) * DHEAD + seg * 8);
        *(uint4*)(KsP + row * 72 + seg * 8) = v;
      }
      __syncthreads();
      #pragma unroll
      for (int ks = 0; ks < 2; ks++){
        bf16x8 aq = ks ? aq1 : aq0;
        #pragma unroll
        for (int c = 0; c < 8; c++){
          bf16x8 bk = *(const bf16x8*)&KsP[(c * 16 + l16) * 72 + ks * 32 + quad * 8];
          S[kh * 8 + c] = __builtin_amdgcn_mfma_f32_16x16x32_bf16(aq, bk, S[kh * 8 + c], 0, 0, 0);
        }
      }
    }

    // ---- softmax in regs; lane holds S[row=quad*4+i][key=c*16+l16] ----
    float mx[4], sm[4];
    #pragma unroll
    for (int i = 0; i < 4; i++) mx[i] = -1e30f;
    #pragma unroll
    for (int c = 0; c < 16; c++)
      #pragma unroll
      for (int i = 0; i < 4; i++){
        float sv = S[c][i] * QSCALE; S[c][i] = sv; mx[i] = fmaxf(mx[i], sv);
      }
    #pragma unroll
    for (int off = 1; off < 16; off <<= 1)
      #pragma unroll
      for (int i = 0; i < 4; i++) mx[i] = fmaxf(mx[i], __shfl_xor(mx[i], off));
    #pragma unroll
    for (int i = 0; i < 4; i++) sm[i] = 0.f;
    #pragma unroll
    for (int c = 0; c < 16; c++)
      #pragma unroll
      for (int i = 0; i < 4; i++){
        float e = __expf(S[c][i] - mx[i]); S[c][i] = e; sm[i] += e;
      }
    #pragma unroll
    for (int off = 1; off < 16; off <<= 1)
      #pragma unroll
      for (int i = 0; i < 4; i++) sm[i] += __shfl_xor(sm[i], off);
    #pragma unroll
    for (int i = 0; i < 4; i++) sm[i] = 1.f / sm[i];

    // ---- PV over two key halves; P half -> KsP (A-layout), V half -> Vh ----
    f32x4 O[4];
    #pragma unroll
    for (int c4 = 0; c4 < 4; c4++) O[c4] = (f32x4){0.f, 0.f, 0.f, 0.f};
    #pragma unroll
    for (int kh = 0; kh < 2; kh++){
      __syncthreads();   // prior KsP/Vh reads done
      #pragma unroll
      for (int c = 0; c < 8; c++)
        #pragma unroll
        for (int i = 0; i < 4; i++)
          KsP[(wave * 16 + quad * 4 + i) * 136 + c * 16 + l16] = f2b(S[kh * 8 + c][i] * sm[i]);
      #pragma unroll
      for (int p = 0; p < 4; p++){
        int idx = p * 256 + t;
        int row = idx >> 4, seg = idx & 15;
        uint4 v = *(const uint4*)(vg + (size_t)row * TM + mi * MTOK + kh * 128 + seg * 8);
        *(uint4*)(Vh + row * 136 + seg * 8) = v;
      }
      __syncthreads();
      #pragma unroll
      for (int k0 = 0; k0 < 4; k0++){
        bf16x8 ap = *(const bf16x8*)&KsP[(wave * 16 + l16) * 136 + k0 * 32 + quad * 8];
        #pragma unroll
        for (int c4 = 0; c4 < 4; c4++){
          bf16x8 bv = *(const bf16x8*)&Vh[(c4 * 16 + l16) * 136 + k0 * 32 + quad * 8];
          O[c4] = __builtin_amdgcn_mfma_f32_16x16x32_bf16(ap, bv, O[c4], 0, 0, 0);
        }
      }
    }

    // ---- write O for queries assigned to this media block ----
    #pragma unroll
    for (int c4 = 0; c4 < 4; c4++)
      #pragma unroll
      for (int i = 0; i < 4; i++){
        int q = wave * 16 + quad * 4 + i;
        if (miq[q] == mi)
          ao[(size_t)(b * TTEXT + q0 + q) * INNER + h * DHEAD + c4 * 16 + l16] = f2b(O[c4][i]);
      }
  }

  // zero rows with no media
  #pragma unroll
  for (int p = 0; p < 16; p++){
    int idx = p * 256 + t;
    int q = idx >> 6, dd = idx & 63;
    if (miq[q] < 0 || miq[q] > 7)
      ao[(size_t)(b * TTEXT + q0 + q) * INNER + h * DHEAD + dd] = 0;
  }
}

extern "C" void kernel_launch(void* const* d_in, const int* in_sizes, int n_in,
                              void* d_out, int out_size, void* d_ws, size_t ws_size,
                              hipStream_t stream){
  const float* x      = (const float*)d_in[0];
  const float* media  = (const float*)d_in[1];
  const unsigned char* locs = (const unsigned char*)d_in[2];
  const float* gamma  = (const float*)d_in[3];
  const float* beta   = (const float*)d_in[4];
  const float* Wq     = (const float*)d_in[5];
  const float* Wkv    = (const float*)d_in[6];
  const float* Wout   = (const float*)d_in[7];

  // workspace layout (~58 MB), all bf16 intermediates
  char* ws = (char*)d_ws;
  int* tt    = (int*)ws;   ws += 16384;
  u16* xn    = (u16*)ws;   ws += (size_t)4096 * 1024 * 2;   // [B*T][DIM]
  u16* medb  = (u16*)ws;   ws += (size_t)4096 * 1024 * 2;   // [B*TM][DIM]
  u16* Wqt   = (u16*)ws;   ws += (size_t)1024 * 1024 * 2;   // [INNER][DIM]
  u16* Wkvt  = (u16*)ws;   ws += (size_t)2048 * 1024 * 2;   // [2*INNER][DIM]
  u16* Woutt = (u16*)ws;   ws += (size_t)1024 * 1024 * 2;   // [DIM][INNER]
  u16* qb    = (u16*)ws;   ws += (size_t)4096 * 1024 * 2;   // [B*T][INNER]
  u16* kB    = (u16*)ws;   ws += (size_t)4096 * 1024 * 2;   // [B,H,TM,64] token-major
  u16* vT    = (u16*)ws;   ws += (size_t)4096 * 1024 * 2;   // [B,H,64,TM] dim-major
  u16* ao    = (u16*)ws;   ws += (size_t)4096 * 1024 * 2;   // [B*T][INNER]

  scan_kernel<<<1, 256, 0, stream>>>(locs, tt);
  ln_kernel<<<BATCH * TTEXT, 256, 0, stream>>>(x, gamma, beta, xn);
  cvt_kernel<<<4096, 256, 0, stream>>>(media, medb);
  transpose_w<<<dim3(32, 32), 256, 0, stream>>>(Wq,   Wqt,   1024, 1024);
  transpose_w<<<dim3(64, 32), 256, 0, stream>>>(Wkv,  Wkvt,  1024, 2048);
  transpose_w<<<dim3(32, 32), 256, 0, stream>>>(Wout, Woutt, 1024, 1024);
  mgemm<0><<<dim3(32, 8),  256, 0, stream>>>(xn,   Wqt,   qb,    nullptr, 4096, 1024, 1024);
  mgemm<2><<<dim3(32, 16), 256, 0, stream>>>(medb, Wkvt,  kB,    vT,      4096, 2048, 1024);
  attn_kernel<<<dim3(64, 16), 256, 0, stream>>>(qb, kB, vT, tt, ao);
  mgemm<1><<<dim3(32, 8),  256, 0, stream>>>(ao,   Woutt, d_out, nullptr, 4096, 1024, 1024);
}

// Round 9
// 217.405 us; speedup vs baseline: 3.4176x; 1.0874x over previous
//
#include <hip/hip_runtime.h>

typedef unsigned short u16;
typedef unsigned int u32;

#define BATCH 2
#define TTEXT 2048
#define DIM 1024
#define TMED 8
#define MTOK 256
#define HEADS 16
#define DHEAD 64
#define INNER 1024
#define TM 2048            // TMED * MTOK
#define QSCALE 0.125f      // DHEAD^-0.5
#define QCHUNK 64          // queries per attention block

typedef __attribute__((ext_vector_type(8))) short bf16x8;
typedef __attribute__((ext_vector_type(4))) float f32x4;

__device__ __forceinline__ float b2f(u16 u){
  union { float f; u32 i; } x; x.i = ((u32)u) << 16; return x.f;
}
__device__ __forceinline__ u16 f2b(float f){
  union { float f; u32 i; } x; x.f = f;
  u32 r = x.i + 0x7FFFu + ((x.i >> 16) & 1u);   // RNE
  return (u16)(r >> 16);
}

#define GLDS16(g, l) __builtin_amdgcn_global_load_lds( \
    (const __attribute__((address_space(1))) u32*)(g), \
    (__attribute__((address_space(3))) u32*)(l), 16, 0, 0)

// ---------------- text_time = cumsum(media_locations) ----------------
__global__ __launch_bounds__(256) void scan_kernel(const unsigned char* __restrict__ raw,
                                                   int* __restrict__ tt){
  int t = threadIdx.x;
  __shared__ int sd[256];
  int c = 0;
  for (int i = t; i < 4096; i += 256) c += (raw[i] != 0);
  sd[t] = c; __syncthreads();
  for (int off = 128; off; off >>= 1){
    if (t < off) sd[t] += sd[t + off];
    __syncthreads();
  }
  int is_byte = (sd[0] >= 9);
  __syncthreads();
  const int* as_int = (const int*)raw;
  for (int b = 0; b < BATCH; b++){
    int inc[8]; int s = 0;
    #pragma unroll
    for (int k = 0; k < 8; k++){
      int i = b * TTEXT + t * 8 + k;
      int v = is_byte ? (raw[i] != 0) : (as_int[i] != 0);
      s += v; inc[k] = s;
    }
    sd[t] = s; __syncthreads();
    for (int off = 1; off < 256; off <<= 1){
      int v = (t >= off) ? sd[t - off] : 0;
      __syncthreads();
      sd[t] += v;
      __syncthreads();
    }
    int excl = sd[t] - s;
    #pragma unroll
    for (int k = 0; k < 8; k++) tt[b * TTEXT + t * 8 + k] = excl + inc[k];
    __syncthreads();
  }
}

// ---------------- LayerNorm: x(fp32) -> xn(bf16) ----------------
__global__ __launch_bounds__(256) void ln_kernel(const float* __restrict__ x,
                                                 const float* __restrict__ gamma,
                                                 const float* __restrict__ beta,
                                                 u16* __restrict__ xn){
  int row = blockIdx.x, t = threadIdx.x;
  float4 v = *(const float4*)(x + (size_t)row * DIM + t * 4);
  float s  = v.x + v.y + v.z + v.w;
  float ss = v.x*v.x + v.y*v.y + v.z*v.z + v.w*v.w;
  #pragma unroll
  for (int off = 32; off; off >>= 1){ s += __shfl_xor(s, off); ss += __shfl_xor(ss, off); }
  __shared__ float ps[4], pss[4];
  __shared__ float mu_s, rs_s;
  int w = t >> 6;
  if ((t & 63) == 0){ ps[w] = s; pss[w] = ss; }
  __syncthreads();
  if (t == 0){
    float S = ps[0] + ps[1] + ps[2] + ps[3];
    float SS = pss[0] + pss[1] + pss[2] + pss[3];
    float mu = S * (1.f / DIM);
    float var = SS * (1.f / DIM) - mu * mu;
    mu_s = mu; rs_s = rsqrtf(var + 1e-5f);
  }
  __syncthreads();
  float mu = mu_s, rs = rs_s;
  float4 g  = *(const float4*)(gamma + t * 4);
  float4 be = *(const float4*)(beta + t * 4);
  ushort4 o;
  o.x = f2b((v.x - mu) * rs * g.x + be.x);
  o.y = f2b((v.y - mu) * rs * g.y + be.y);
  o.z = f2b((v.z - mu) * rs * g.z + be.z);
  o.w = f2b((v.w - mu) * rs * g.w + be.w);
  *(ushort4*)(xn + (size_t)row * DIM + t * 4) = o;
}

// ---------------- fp32 -> bf16 elementwise (media) ----------------
__global__ __launch_bounds__(256) void cvt_kernel(const float* __restrict__ in,
                                                  u16* __restrict__ out){
  int i = (blockIdx.x * 256 + threadIdx.x) * 4;
  float4 v = *(const float4*)(in + i);
  ushort4 o;
  o.x = f2b(v.x); o.y = f2b(v.y); o.z = f2b(v.z); o.w = f2b(v.w);
  *(ushort4*)(out + i) = o;
}

// ---------------- all three W [K][N] fp32 -> Wt [N][K] bf16, one dispatch ----------------
__global__ __launch_bounds__(256) void transpose3(const float* __restrict__ Wq,
                                                  const float* __restrict__ Wkv,
                                                  const float* __restrict__ Wout,
                                                  u16* __restrict__ Wqt,
                                                  u16* __restrict__ Wkvt,
                                                  u16* __restrict__ Woutt){
  __shared__ float tile[32][33];
  int z = blockIdx.z;
  const float* W; u16* Wt; int N; int bx = blockIdx.x;
  if (z == 0){ W = Wq;   Wt = Wqt;   N = 1024; }
  else if (z == 1){ W = Wout; Wt = Woutt; N = 1024; }
  else { W = Wkv; Wt = Wkvt; N = 2048; bx += (z - 2) * 32; }
  const int K = 1024;
  int by = blockIdx.y;            // along K
  int tx = threadIdx.x & 31, ty = threadIdx.x >> 5;   // 32 x 8
  int n = bx * 32 + tx;
  #pragma unroll
  for (int i = 0; i < 32; i += 8)
    tile[ty + i][tx] = W[(size_t)(by * 32 + ty + i) * N + n];
  __syncthreads();
  int k2 = by * 32 + tx;
  #pragma unroll
  for (int i = 0; i < 32; i += 8)
    Wt[(size_t)(bx * 32 + ty + i) * K + k2] = f2b(tile[tx][ty + i]);
}

// ---------------- MFMA GEMM: C[M,N] = A[M,K] @ Bt[N,K]^T, bf16 in ----------------
// MODE 0: bf16 C [M][N].  MODE 1: fp32 C [M][N].
// MODE 2: KV scatter bf16 -> K token-major [B,H,TM,64] (Cp), V dim-major [B,H,64,TM] (C2p).
template<int MODE>
__global__ __launch_bounds__(256) void mgemm(const u16* __restrict__ A,
                                             const u16* __restrict__ Bt,
                                             void* __restrict__ Cp,
                                             u16* __restrict__ C2p,
                                             int M, int N, int K){
  __shared__ u16 As[128 * 32];    // [row][k], row stride 32 elems = 64B
  __shared__ u16 Bs[128 * 32];    // [col][k]
  int tid = threadIdx.x;
  int wave = tid >> 6, lane = tid & 63;
  int m0 = blockIdx.x * 128, n0 = blockIdx.y * 128;
  int wm = (wave & 1) * 64, wn = (wave >> 1) * 64;
  int quad = lane >> 4, l16 = lane & 15;

  f32x4 acc[4][4];
  #pragma unroll
  for (int r = 0; r < 4; r++)
    #pragma unroll
    for (int c = 0; c < 4; c++) acc[r][c] = (f32x4){0.f, 0.f, 0.f, 0.f};

  const u16* ag = A  + (size_t)(m0 + wave * 32 + (lane >> 2)) * K + (lane & 3) * 8;
  const u16* bg = Bt + (size_t)(n0 + wave * 32 + (lane >> 2)) * K + (lane & 3) * 8;
  u16* asl = As + wave * 32 * 32;
  u16* bsl = Bs + wave * 32 * 32;

  for (int k0 = 0; k0 < K; k0 += 32){
    GLDS16(ag + k0,                  asl);
    GLDS16(ag + k0 + 16 * (size_t)K, asl + 16 * 32);
    GLDS16(bg + k0,                  bsl);
    GLDS16(bg + k0 + 16 * (size_t)K, bsl + 16 * 32);
    __syncthreads();
    bf16x8 af[4], bf[4];
    #pragma unroll
    for (int r = 0; r < 4; r++)
      af[r] = *(const bf16x8*)&As[(wm + r * 16 + l16) * 32 + quad * 8];
    #pragma unroll
    for (int c = 0; c < 4; c++)
      bf[c] = *(const bf16x8*)&Bs[(wn + c * 16 + l16) * 32 + quad * 8];
    #pragma unroll
    for (int r = 0; r < 4; r++)
      #pragma unroll
      for (int c = 0; c < 4; c++)
        acc[r][c] = __builtin_amdgcn_mfma_f32_16x16x32_bf16(af[r], bf[c], acc[r][c], 0, 0, 0);
    __syncthreads();
  }

  #pragma unroll
  for (int r = 0; r < 4; r++){
    #pragma unroll
    for (int c = 0; c < 4; c++){
      int rG = m0 + wm + r * 16 + quad * 4;      // + i
      int cG = n0 + wn + c * 16 + l16;
      if (MODE == 0){
        u16* C = (u16*)Cp;
        #pragma unroll
        for (int i = 0; i < 4; i++)
          C[(size_t)(rG + i) * N + cG] = f2b(acc[r][c][i]);
      } else if (MODE == 1){
        float* C = (float*)Cp;
        #pragma unroll
        for (int i = 0; i < 4; i++)
          C[(size_t)(rG + i) * N + cG] = acc[r][c][i];
      } else {
        int bb = rG >> 11, jj = rG & 2047;       // 4-row groups never cross batch
        if (cG < INNER){
          // K token-major: kB[((b*H+h)*TM + token)*64 + d]
          int hh = cG >> 6, dd = cG & 63;
          u16* kp = (u16*)Cp + (((size_t)bb * HEADS + hh) * TM + jj) * DHEAD + dd;
          #pragma unroll
          for (int i = 0; i < 4; i++)
            kp[(size_t)i * DHEAD] = f2b(acc[r][c][i]);
        } else {
          // V dim-major: vT[((b*H+h)*64 + d)*TM + token]
          int cc = cG - INNER;
          int hh = cc >> 6, dd = cc & 63;
          u16* vp = C2p + (((size_t)bb * HEADS + hh) * DHEAD + dd) * TM + jj;
          ushort4 o;
          o.x = f2b(acc[r][c][0]); o.y = f2b(acc[r][c][1]);
          o.z = f2b(acc[r][c][2]); o.w = f2b(acc[r][c][3]);
          *(ushort4*)vp = o;
        }
      }
    }
  }
}

// ---------------- MFMA attention: 64 queries x 1 head per block ----------------
// Round-8 proven core + (1) XCD swizzle: 1-D grid, id = chunk*32 + (b*16+h),
// so id%8 is constant per (b,h) -> all chunks of one (b,h) share an XCD's L2
// (per-XCD KV working set 2 MB < 4 MB L2); (2) registered O select across mi
// with ONE coalesced dwordx4 store at the end (via intra-wave LDS transpose,
// no barrier) -- kills scalar-store RMW write amplification + zero-fill pass.
__global__ __launch_bounds__(256, 3) void attn_kernel(const u16* __restrict__ qb,
                                                      const u16* __restrict__ kB,
                                                      const u16* __restrict__ vT,
                                                      const int* __restrict__ tt,
                                                      u16* __restrict__ ao){
  __shared__ u16 KsP[128 * 72];        // K half [128 keys][72]; P half [64 q][136]; O strip [64 q][72]
  __shared__ u16 Vh[64 * 136];         // V half [64 d][128 keys pad->136]
  __shared__ int miq[QCHUNK];
  __shared__ int present[8];

  int t = threadIdx.x;
  int wave = t >> 6, lane = t & 63, quad = lane >> 4, l16 = lane & 15;
  int id = blockIdx.x;
  int pair = id & 31, chunk = id >> 5;  // XCD swizzle: id%8 == pair%8 fixed per (b,h)
  int b = pair >> 4, h = pair & 15;
  int q0 = chunk * QCHUNK;

  if (t < 8) present[t] = 0;
  __syncthreads();
  if (t < QCHUNK){
    int v = tt[b * TTEXT + q0 + t] - 1;
    miq[t] = v;
    if (v >= 0 && v < 8) present[v] = 1;
  }
  // Q fragments direct from global: q row = wave*16 + l16, d = ks*32 + quad*8
  const u16* qrow = qb + (size_t)(b * TTEXT + q0 + wave * 16 + l16) * INNER
                       + h * DHEAD + quad * 8;
  bf16x8 aq0 = *(const bf16x8*)(qrow);
  bf16x8 aq1 = *(const bf16x8*)(qrow + 32);
  __syncthreads();                     // miq/present visible to all

  int myi[4];
  #pragma unroll
  for (int i = 0; i < 4; i++) myi[i] = miq[wave * 16 + quad * 4 + i];

  const size_t kvh = (size_t)b * HEADS + h;
  const u16* kg = kB + kvh * TM * DHEAD;            // [token][64]
  const u16* vg = vT + kvh * DHEAD * TM;            // [d][TM]

  f32x4 Osel[4];
  #pragma unroll
  for (int c4 = 0; c4 < 4; c4++) Osel[c4] = (f32x4){0.f, 0.f, 0.f, 0.f};

  for (int mi = 0; mi < 8; mi++){
    if (!present[mi]) continue;                     // block-uniform

    // ---- QK^T over two 128-key halves staged into KsP ----
    f32x4 S[16];
    #pragma unroll
    for (int c = 0; c < 16; c++) S[c] = (f32x4){0.f, 0.f, 0.f, 0.f};
    #pragma unroll
    for (int kh = 0; kh < 2; kh++){
      __syncthreads();   // prior KsP reads done (prev half QK / prev mi P)
      #pragma unroll
      for (int p = 0; p < 4; p++){
        int idx = p * 256 + t;
        int row = idx >> 3, seg = idx & 7;
        uint4 v = *(const uint4*)(kg + (size_t)(mi * MTOK + kh * 128 + row) * DHEAD + seg * 8);
        *(uint4*)(KsP + row * 72 + seg * 8) = v;
      }
      __syncthreads();
      #pragma unroll
      for (int ks = 0; ks < 2; ks++){
        bf16x8 aq = ks ? aq1 : aq0;
        #pragma unroll
        for (int c = 0; c < 8; c++){
          bf16x8 bk = *(const bf16x8*)&KsP[(c * 16 + l16) * 72 + ks * 32 + quad * 8];
          S[kh * 8 + c] = __builtin_amdgcn_mfma_f32_16x16x32_bf16(aq, bk, S[kh * 8 + c], 0, 0, 0);
        }
      }
    }

    // ---- softmax in regs; lane holds S[row=quad*4+i][key=c*16+l16] ----
    float mx[4], sm[4];
    #pragma unroll
    for (int i = 0; i < 4; i++) mx[i] = -1e30f;
    #pragma unroll
    for (int c = 0; c < 16; c++)
      #pragma unroll
      for (int i = 0; i < 4; i++){
        float sv = S[c][i] * QSCALE; S[c][i] = sv; mx[i] = fmaxf(mx[i], sv);
      }
    #pragma unroll
    for (int off = 1; off < 16; off <<= 1)
      #pragma unroll
      for (int i = 0; i < 4; i++) mx[i] = fmaxf(mx[i], __shfl_xor(mx[i], off));
    #pragma unroll
    for (int i = 0; i < 4; i++) sm[i] = 0.f;
    #pragma unroll
    for (int c = 0; c < 16; c++)
      #pragma unroll
      for (int i = 0; i < 4; i++){
        float e = __expf(S[c][i] - mx[i]); S[c][i] = e; sm[i] += e;
      }
    #pragma unroll
    for (int off = 1; off < 16; off <<= 1)
      #pragma unroll
      for (int i = 0; i < 4; i++) sm[i] += __shfl_xor(sm[i], off);
    #pragma unroll
    for (int i = 0; i < 4; i++) sm[i] = 1.f / sm[i];

    // ---- PV over two key halves; P half -> KsP (A-layout), V half -> Vh ----
    f32x4 O[4];
    #pragma unroll
    for (int c4 = 0; c4 < 4; c4++) O[c4] = (f32x4){0.f, 0.f, 0.f, 0.f};
    #pragma unroll
    for (int kh = 0; kh < 2; kh++){
      __syncthreads();   // prior KsP/Vh reads done
      #pragma unroll
      for (int c = 0; c < 8; c++)
        #pragma unroll
        for (int i = 0; i < 4; i++)
          KsP[(wave * 16 + quad * 4 + i) * 136 + c * 16 + l16] = f2b(S[kh * 8 + c][i] * sm[i]);
      #pragma unroll
      for (int p = 0; p < 4; p++){
        int idx = p * 256 + t;
        int row = idx >> 4, seg = idx & 15;
        uint4 v = *(const uint4*)(vg + (size_t)row * TM + mi * MTOK + kh * 128 + seg * 8);
        *(uint4*)(Vh + row * 136 + seg * 8) = v;
      }
      __syncthreads();
      #pragma unroll
      for (int k0 = 0; k0 < 4; k0++){
        bf16x8 ap = *(const bf16x8*)&KsP[(wave * 16 + l16) * 136 + k0 * 32 + quad * 8];
        #pragma unroll
        for (int c4 = 0; c4 < 4; c4++){
          bf16x8 bv = *(const bf16x8*)&Vh[(c4 * 16 + l16) * 136 + k0 * 32 + quad * 8];
          O[c4] = __builtin_amdgcn_mfma_f32_16x16x32_bf16(ap, bv, O[c4], 0, 0, 0);
        }
      }
    }

    // ---- select into registered output (row matches exactly <=1 mi) ----
    #pragma unroll
    for (int c4 = 0; c4 < 4; c4++)
      #pragma unroll
      for (int i = 0; i < 4; i++)
        Osel[c4][i] = (myi[i] == mi) ? O[c4][i] : Osel[c4][i];
  }

  // ---- single coalesced O write: intra-wave LDS transpose (own 16-row strip,
  // stride 72; no barrier needed: same-wave ds_write -> ds_read) ----
  #pragma unroll
  for (int c4 = 0; c4 < 4; c4++)
    #pragma unroll
    for (int i = 0; i < 4; i++)
      KsP[(wave * 16 + quad * 4 + i) * 72 + c4 * 16 + l16] = f2b(Osel[c4][i]);
  int r = lane >> 2, sidx = lane & 3;
  #pragma unroll
  for (int p = 0; p < 2; p++){
    int seg = p * 4 + sidx;
    uint4 v = *(const uint4*)&KsP[(wave * 16 + r) * 72 + seg * 8];
    *(uint4*)(ao + (size_t)(b * TTEXT + q0 + wave * 16 + r) * INNER + h * DHEAD + seg * 8) = v;
  }
}

extern "C" void kernel_launch(void* const* d_in, const int* in_sizes, int n_in,
                              void* d_out, int out_size, void* d_ws, size_t ws_size,
                              hipStream_t stream){
  const float* x      = (const float*)d_in[0];
  const float* media  = (const float*)d_in[1];
  const unsigned char* locs = (const unsigned char*)d_in[2];
  const float* gamma  = (const float*)d_in[3];
  const float* beta   = (const float*)d_in[4];
  const float* Wq     = (const float*)d_in[5];
  const float* Wkv    = (const float*)d_in[6];
  const float* Wout   = (const float*)d_in[7];

  // workspace layout (~58 MB), all bf16 intermediates
  char* ws = (char*)d_ws;
  int* tt    = (int*)ws;   ws += 16384;
  u16* xn    = (u16*)ws;   ws += (size_t)4096 * 1024 * 2;   // [B*T][DIM]
  u16* medb  = (u16*)ws;   ws += (size_t)4096 * 1024 * 2;   // [B*TM][DIM]
  u16* Wqt   = (u16*)ws;   ws += (size_t)1024 * 1024 * 2;   // [INNER][DIM]
  u16* Wkvt  = (u16*)ws;   ws += (size_t)2048 * 1024 * 2;   // [2*INNER][DIM]
  u16* Woutt = (u16*)ws;   ws += (size_t)1024 * 1024 * 2;   // [DIM][INNER]
  u16* qb    = (u16*)ws;   ws += (size_t)4096 * 1024 * 2;   // [B*T][INNER]
  u16* kB    = (u16*)ws;   ws += (size_t)4096 * 1024 * 2;   // [B,H,TM,64] token-major
  u16* vT    = (u16*)ws;   ws += (size_t)4096 * 1024 * 2;   // [B,H,64,TM] dim-major
  u16* ao    = (u16*)ws;   ws += (size_t)4096 * 1024 * 2;   // [B*T][INNER]

  scan_kernel<<<1, 256, 0, stream>>>(locs, tt);
  ln_kernel<<<BATCH * TTEXT, 256, 0, stream>>>(x, gamma, beta, xn);
  cvt_kernel<<<4096, 256, 0, stream>>>(media, medb);
  transpose3<<<dim3(32, 32, 4), 256, 0, stream>>>(Wq, Wkv, Wout, Wqt, Wkvt, Woutt);
  mgemm<0><<<dim3(32, 8),  256, 0, stream>>>(xn,   Wqt,   qb,    nullptr, 4096, 1024, 1024);
  mgemm<2><<<dim3(32, 16), 256, 0, stream>>>(medb, Wkvt,  kB,    vT,      4096, 2048, 1024);
  attn_kernel<<<dim3(1024), 256, 0, stream>>>(qb, kB, vT, tt, ao);
  mgemm<1><<<dim3(32, 8),  256, 0, stream>>>(ao,   Woutt, d_out, nullptr, 4096, 1024, 1024);
}

// Round 10
// 202.715 us; speedup vs baseline: 3.6653x; 1.0725x over previous
//
#include <hip/hip_runtime.h>

typedef unsigned short u16;
typedef unsigned int u32;

#define BATCH 2
#define TTEXT 2048
#define DIM 1024
#define TMED 8
#define MTOK 256
#define HEADS 16
#define DHEAD 64
#define INNER 1024
#define TM 2048            // TMED * MTOK
#define QSCALE 0.125f      // DHEAD^-0.5
#define QCHUNK 64          // queries per attention block

typedef __attribute__((ext_vector_type(8))) short bf16x8;
typedef __attribute__((ext_vector_type(4))) float f32x4;

__device__ __forceinline__ float b2f(u16 u){
  union { float f; u32 i; } x; x.i = ((u32)u) << 16; return x.f;
}
__device__ __forceinline__ u16 f2b(float f){
  union { float f; u32 i; } x; x.f = f;
  u32 r = x.i + 0x7FFFu + ((x.i >> 16) & 1u);   // RNE
  return (u16)(r >> 16);
}

#define GLDS16(g, l) __builtin_amdgcn_global_load_lds( \
    (const __attribute__((address_space(1))) u32*)(g), \
    (__attribute__((address_space(3))) u32*)(l), 16, 0, 0)

// ---------------- text_time = cumsum(media_locations) ----------------
__global__ __launch_bounds__(256) void scan_kernel(const unsigned char* __restrict__ raw,
                                                   int* __restrict__ tt){
  int t = threadIdx.x;
  __shared__ int sd[256];
  int c = 0;
  for (int i = t; i < 4096; i += 256) c += (raw[i] != 0);
  sd[t] = c; __syncthreads();
  for (int off = 128; off; off >>= 1){
    if (t < off) sd[t] += sd[t + off];
    __syncthreads();
  }
  int is_byte = (sd[0] >= 9);
  __syncthreads();
  const int* as_int = (const int*)raw;
  for (int b = 0; b < BATCH; b++){
    int inc[8]; int s = 0;
    #pragma unroll
    for (int k = 0; k < 8; k++){
      int i = b * TTEXT + t * 8 + k;
      int v = is_byte ? (raw[i] != 0) : (as_int[i] != 0);
      s += v; inc[k] = s;
    }
    sd[t] = s; __syncthreads();
    for (int off = 1; off < 256; off <<= 1){
      int v = (t >= off) ? sd[t - off] : 0;
      __syncthreads();
      sd[t] += v;
      __syncthreads();
    }
    int excl = sd[t] - s;
    #pragma unroll
    for (int k = 0; k < 8; k++) tt[b * TTEXT + t * 8 + k] = excl + inc[k];
    __syncthreads();
  }
}

// ---------------- LayerNorm: x(fp32) -> xn(bf16) ----------------
__global__ __launch_bounds__(256) void ln_kernel(const float* __restrict__ x,
                                                 const float* __restrict__ gamma,
                                                 const float* __restrict__ beta,
                                                 u16* __restrict__ xn){
  int row = blockIdx.x, t = threadIdx.x;
  float4 v = *(const float4*)(x + (size_t)row * DIM + t * 4);
  float s  = v.x + v.y + v.z + v.w;
  float ss = v.x*v.x + v.y*v.y + v.z*v.z + v.w*v.w;
  #pragma unroll
  for (int off = 32; off; off >>= 1){ s += __shfl_xor(s, off); ss += __shfl_xor(ss, off); }
  __shared__ float ps[4], pss[4];
  __shared__ float mu_s, rs_s;
  int w = t >> 6;
  if ((t & 63) == 0){ ps[w] = s; pss[w] = ss; }
  __syncthreads();
  if (t == 0){
    float S = ps[0] + ps[1] + ps[2] + ps[3];
    float SS = pss[0] + pss[1] + pss[2] + pss[3];
    float mu = S * (1.f / DIM);
    float var = SS * (1.f / DIM) - mu * mu;
    mu_s = mu; rs_s = rsqrtf(var + 1e-5f);
  }
  __syncthreads();
  float mu = mu_s, rs = rs_s;
  float4 g  = *(const float4*)(gamma + t * 4);
  float4 be = *(const float4*)(beta + t * 4);
  ushort4 o;
  o.x = f2b((v.x - mu) * rs * g.x + be.x);
  o.y = f2b((v.y - mu) * rs * g.y + be.y);
  o.z = f2b((v.z - mu) * rs * g.z + be.z);
  o.w = f2b((v.w - mu) * rs * g.w + be.w);
  *(ushort4*)(xn + (size_t)row * DIM + t * 4) = o;
}

// ---------------- fp32 -> bf16 elementwise (media) ----------------
__global__ __launch_bounds__(256) void cvt_kernel(const float* __restrict__ in,
                                                  u16* __restrict__ out){
  int i = (blockIdx.x * 256 + threadIdx.x) * 4;
  float4 v = *(const float4*)(in + i);
  ushort4 o;
  o.x = f2b(v.x); o.y = f2b(v.y); o.z = f2b(v.z); o.w = f2b(v.w);
  *(ushort4*)(out + i) = o;
}

// ---------------- all three W [K][N] fp32 -> Wt [N][K] bf16, one dispatch ----------------
__global__ __launch_bounds__(256) void transpose3(const float* __restrict__ Wq,
                                                  const float* __restrict__ Wkv,
                                                  const float* __restrict__ Wout,
                                                  u16* __restrict__ Wqt,
                                                  u16* __restrict__ Wkvt,
                                                  u16* __restrict__ Woutt){
  __shared__ float tile[32][33];
  int z = blockIdx.z;
  const float* W; u16* Wt; int N; int bx = blockIdx.x;
  if (z == 0){ W = Wq;   Wt = Wqt;   N = 1024; }
  else if (z == 1){ W = Wout; Wt = Woutt; N = 1024; }
  else { W = Wkv; Wt = Wkvt; N = 2048; bx += (z - 2) * 32; }
  const int K = 1024;
  int by = blockIdx.y;            // along K
  int tx = threadIdx.x & 31, ty = threadIdx.x >> 5;   // 32 x 8
  int n = bx * 32 + tx;
  #pragma unroll
  for (int i = 0; i < 32; i += 8)
    tile[ty + i][tx] = W[(size_t)(by * 32 + ty + i) * N + n];
  __syncthreads();
  int k2 = by * 32 + tx;
  #pragma unroll
  for (int i = 0; i < 32; i += 8)
    Wt[(size_t)(bx * 32 + ty + i) * K + k2] = f2b(tile[tx][ty + i]);
}

// ---------------- MFMA GEMM: C[M,N] = A[M,K] @ Bt[N,K]^T, bf16 in ----------------
// Double-buffered LDS, ONE barrier per K-step: stage(k+1) issued right after
// the barrier overlaps with compute(k); its vmcnt drain at the next barrier has
// had the whole compute phase to complete. BN=64 -> 128x64 tile (2x blocks for
// 1-block/CU shapes); BN=128 -> classic 128x128.
// MODE 0: bf16 C [M][N].  MODE 1: fp32 C [M][N].
// MODE 2: KV scatter bf16 -> K token-major [B,H,TM,64] (Cp), V dim-major [B,H,64,TM] (C2p).
template<int MODE, int BN>
__global__ __launch_bounds__(256) void mgemm(const u16* __restrict__ A,
                                             const u16* __restrict__ Bt,
                                             void* __restrict__ Cp,
                                             u16* __restrict__ C2p,
                                             int M, int N, int K){
  constexpr int BCOLS = BN / 32;         // 16-col tiles per wave in N
  __shared__ u16 As[2 * 128 * 32];       // [buf][row][k], row stride 32 elems
  __shared__ u16 Bs[2 * BN * 32];
  int tid = threadIdx.x;
  int wave = tid >> 6, lane = tid & 63;
  int m0 = blockIdx.x * 128, n0 = blockIdx.y * BN;
  int wm = (wave & 1) * 64, wn = (wave >> 1) * (BN / 2);
  int quad = lane >> 4, l16 = lane & 15;

  f32x4 acc[4][BCOLS];
  #pragma unroll
  for (int r = 0; r < 4; r++)
    #pragma unroll
    for (int c = 0; c < BCOLS; c++) acc[r][c] = (f32x4){0.f, 0.f, 0.f, 0.f};

  const u16* ag = A + (size_t)(m0 + wave * 32 + (lane >> 2)) * K + (lane & 3) * 8;
  const u16* bg;
  u16* asl0 = As + wave * 32 * 32;
  u16* bsl0;
  if (BN == 128){
    bg = Bt + (size_t)(n0 + wave * 32 + (lane >> 2)) * K + (lane & 3) * 8;
    bsl0 = Bs + wave * 32 * 32;
  } else {
    bg = Bt + (size_t)(n0 + wave * 16 + (lane >> 2)) * K + (lane & 3) * 8;
    bsl0 = Bs + wave * 16 * 32;
  }

  auto stage = [&](int k0, int buf){
    u16* asl = asl0 + buf * 128 * 32;
    u16* bsl = bsl0 + buf * BN * 32;
    GLDS16(ag + k0,                  asl);
    GLDS16(ag + k0 + 16 * (size_t)K, asl + 16 * 32);
    GLDS16(bg + k0,                  bsl);
    if (BN == 128) GLDS16(bg + k0 + 16 * (size_t)K, bsl + 16 * 32);
  };

  int steps = K >> 5;
  stage(0, 0);
  for (int s = 0; s < steps; s++){
    __syncthreads();                     // drains stage(s); frees buf[(s+1)&1] for overwrite
    if (s + 1 < steps) stage((s + 1) << 5, (s + 1) & 1);
    const u16* Ab = As + (s & 1) * 128 * 32;
    const u16* Bb = Bs + (s & 1) * BN * 32;
    bf16x8 af[4], bf[BCOLS];
    #pragma unroll
    for (int r = 0; r < 4; r++)
      af[r] = *(const bf16x8*)&Ab[(wm + r * 16 + l16) * 32 + quad * 8];
    #pragma unroll
    for (int c = 0; c < BCOLS; c++)
      bf[c] = *(const bf16x8*)&Bb[(wn + c * 16 + l16) * 32 + quad * 8];
    #pragma unroll
    for (int r = 0; r < 4; r++)
      #pragma unroll
      for (int c = 0; c < BCOLS; c++)
        acc[r][c] = __builtin_amdgcn_mfma_f32_16x16x32_bf16(af[r], bf[c], acc[r][c], 0, 0, 0);
  }

  #pragma unroll
  for (int r = 0; r < 4; r++){
    #pragma unroll
    for (int c = 0; c < BCOLS; c++){
      int rG = m0 + wm + r * 16 + quad * 4;      // + i
      int cG = n0 + wn + c * 16 + l16;
      if (MODE == 0){
        u16* C = (u16*)Cp;
        #pragma unroll
        for (int i = 0; i < 4; i++)
          C[(size_t)(rG + i) * N + cG] = f2b(acc[r][c][i]);
      } else if (MODE == 1){
        float* C = (float*)Cp;
        #pragma unroll
        for (int i = 0; i < 4; i++)
          C[(size_t)(rG + i) * N + cG] = acc[r][c][i];
      } else {
        int bb = rG >> 11, jj = rG & 2047;       // 4-row groups never cross batch
        if (cG < INNER){
          // K token-major: kB[((b*H+h)*TM + token)*64 + d]
          int hh = cG >> 6, dd = cG & 63;
          u16* kp = (u16*)Cp + (((size_t)bb * HEADS + hh) * TM + jj) * DHEAD + dd;
          #pragma unroll
          for (int i = 0; i < 4; i++)
            kp[(size_t)i * DHEAD] = f2b(acc[r][c][i]);
        } else {
          // V dim-major: vT[((b*H+h)*64 + d)*TM + token]
          int cc = cG - INNER;
          int hh = cc >> 6, dd = cc & 63;
          u16* vp = C2p + (((size_t)bb * HEADS + hh) * DHEAD + dd) * TM + jj;
          ushort4 o;
          o.x = f2b(acc[r][c][0]); o.y = f2b(acc[r][c][1]);
          o.z = f2b(acc[r][c][2]); o.w = f2b(acc[r][c][3]);
          *(ushort4*)vp = o;
        }
      }
    }
  }
}

// ---------------- MFMA attention: 64 queries x 1 head per block ----------------
// Round-9 green version (XCD swizzle + registered O select + single coalesced write).
__global__ __launch_bounds__(256, 3) void attn_kernel(const u16* __restrict__ qb,
                                                      const u16* __restrict__ kB,
                                                      const u16* __restrict__ vT,
                                                      const int* __restrict__ tt,
                                                      u16* __restrict__ ao){
  __shared__ u16 KsP[128 * 72];        // K half [128 keys][72]; P half [64 q][136]; O strip [64 q][72]
  __shared__ u16 Vh[64 * 136];         // V half [64 d][128 keys pad->136]
  __shared__ int miq[QCHUNK];
  __shared__ int present[8];

  int t = threadIdx.x;
  int wave = t >> 6, lane = t & 63, quad = lane >> 4, l16 = lane & 15;
  int id = blockIdx.x;
  int pair = id & 31, chunk = id >> 5;  // XCD swizzle: id%8 == pair%8 fixed per (b,h)
  int b = pair >> 4, h = pair & 15;
  int q0 = chunk * QCHUNK;

  if (t < 8) present[t] = 0;
  __syncthreads();
  if (t < QCHUNK){
    int v = tt[b * TTEXT + q0 + t] - 1;
    miq[t] = v;
    if (v >= 0 && v < 8) present[v] = 1;
  }
  const u16* qrow = qb + (size_t)(b * TTEXT + q0 + wave * 16 + l16) * INNER
                       + h * DHEAD + quad * 8;
  bf16x8 aq0 = *(const bf16x8*)(qrow);
  bf16x8 aq1 = *(const bf16x8*)(qrow + 32);
  __syncthreads();                     // miq/present visible to all

  int myi[4];
  #pragma unroll
  for (int i = 0; i < 4; i++) myi[i] = miq[wave * 16 + quad * 4 + i];

  const size_t kvh = (size_t)b * HEADS + h;
  const u16* kg = kB + kvh * TM * DHEAD;            // [token][64]
  const u16* vg = vT + kvh * DHEAD * TM;            // [d][TM]

  f32x4 Osel[4];
  #pragma unroll
  for (int c4 = 0; c4 < 4; c4++) Osel[c4] = (f32x4){0.f, 0.f, 0.f, 0.f};

  for (int mi = 0; mi < 8; mi++){
    if (!present[mi]) continue;                     // block-uniform

    f32x4 S[16];
    #pragma unroll
    for (int c = 0; c < 16; c++) S[c] = (f32x4){0.f, 0.f, 0.f, 0.f};
    #pragma unroll
    for (int kh = 0; kh < 2; kh++){
      __syncthreads();   // prior KsP reads done (prev half QK / prev mi P)
      #pragma unroll
      for (int p = 0; p < 4; p++){
        int idx = p * 256 + t;
        int row = idx >> 3, seg = idx & 7;
        uint4 v = *(const uint4*)(kg + (size_t)(mi * MTOK + kh * 128 + row) * DHEAD + seg * 8);
        *(uint4*)(KsP + row * 72 + seg * 8) = v;
      }
      __syncthreads();
      #pragma unroll
      for (int ks = 0; ks < 2; ks++){
        bf16x8 aq = ks ? aq1 : aq0;
        #pragma unroll
        for (int c = 0; c < 8; c++){
          bf16x8 bk = *(const bf16x8*)&KsP[(c * 16 + l16) * 72 + ks * 32 + quad * 8];
          S[kh * 8 + c] = __builtin_amdgcn_mfma_f32_16x16x32_bf16(aq, bk, S[kh * 8 + c], 0, 0, 0);
        }
      }
    }

    float mx[4], sm[4];
    #pragma unroll
    for (int i = 0; i < 4; i++) mx[i] = -1e30f;
    #pragma unroll
    for (int c = 0; c < 16; c++)
      #pragma unroll
      for (int i = 0; i < 4; i++){
        float sv = S[c][i] * QSCALE; S[c][i] = sv; mx[i] = fmaxf(mx[i], sv);
      }
    #pragma unroll
    for (int off = 1; off < 16; off <<= 1)
      #pragma unroll
      for (int i = 0; i < 4; i++) mx[i] = fmaxf(mx[i], __shfl_xor(mx[i], off));
    #pragma unroll
    for (int i = 0; i < 4; i++) sm[i] = 0.f;
    #pragma unroll
    for (int c = 0; c < 16; c++)
      #pragma unroll
      for (int i = 0; i < 4; i++){
        float e = __expf(S[c][i] - mx[i]); S[c][i] = e; sm[i] += e;
      }
    #pragma unroll
    for (int off = 1; off < 16; off <<= 1)
      #pragma unroll
      for (int i = 0; i < 4; i++) sm[i] += __shfl_xor(sm[i], off);
    #pragma unroll
    for (int i = 0; i < 4; i++) sm[i] = 1.f / sm[i];

    f32x4 O[4];
    #pragma unroll
    for (int c4 = 0; c4 < 4; c4++) O[c4] = (f32x4){0.f, 0.f, 0.f, 0.f};
    #pragma unroll
    for (int kh = 0; kh < 2; kh++){
      __syncthreads();   // prior KsP/Vh reads done
      #pragma unroll
      for (int c = 0; c < 8; c++)
        #pragma unroll
        for (int i = 0; i < 4; i++)
          KsP[(wave * 16 + quad * 4 + i) * 136 + c * 16 + l16] = f2b(S[kh * 8 + c][i] * sm[i]);
      #pragma unroll
      for (int p = 0; p < 4; p++){
        int idx = p * 256 + t;
        int row = idx >> 4, seg = idx & 15;
        uint4 v = *(const uint4*)(vg + (size_t)row * TM + mi * MTOK + kh * 128 + seg * 8);
        *(uint4*)(Vh + row * 136 + seg * 8) = v;
      }
      __syncthreads();
      #pragma unroll
      for (int k0 = 0; k0 < 4; k0++){
        bf16x8 ap = *(const bf16x8*)&KsP[(wave * 16 + l16) * 136 + k0 * 32 + quad * 8];
        #pragma unroll
        for (int c4 = 0; c4 < 4; c4++){
          bf16x8 bv = *(const bf16x8*)&Vh[(c4 * 16 + l16) * 136 + k0 * 32 + quad * 8];
          O[c4] = __builtin_amdgcn_mfma_f32_16x16x32_bf16(ap, bv, O[c4], 0, 0, 0);
        }
      }
    }

    #pragma unroll
    for (int c4 = 0; c4 < 4; c4++)
      #pragma unroll
      for (int i = 0; i < 4; i++)
        Osel[c4][i] = (myi[i] == mi) ? O[c4][i] : Osel[c4][i];
  }

  // single coalesced O write via intra-wave LDS transpose (own strip, no barrier)
  #pragma unroll
  for (int c4 = 0; c4 < 4; c4++)
    #pragma unroll
    for (int i = 0; i < 4; i++)
      KsP[(wave * 16 + quad * 4 + i) * 72 + c4 * 16 + l16] = f2b(Osel[c4][i]);
  int r = lane >> 2, sidx = lane & 3;
  #pragma unroll
  for (int p = 0; p < 2; p++){
    int seg = p * 4 + sidx;
    uint4 v = *(const uint4*)&KsP[(wave * 16 + r) * 72 + seg * 8];
    *(uint4*)(ao + (size_t)(b * TTEXT + q0 + wave * 16 + r) * INNER + h * DHEAD + seg * 8) = v;
  }
}

extern "C" void kernel_launch(void* const* d_in, const int* in_sizes, int n_in,
                              void* d_out, int out_size, void* d_ws, size_t ws_size,
                              hipStream_t stream){
  const float* x      = (const float*)d_in[0];
  const float* media  = (const float*)d_in[1];
  const unsigned char* locs = (const unsigned char*)d_in[2];
  const float* gamma  = (const float*)d_in[3];
  const float* beta   = (const float*)d_in[4];
  const float* Wq     = (const float*)d_in[5];
  const float* Wkv    = (const float*)d_in[6];
  const float* Wout   = (const float*)d_in[7];

  // workspace layout (~58 MB), all bf16 intermediates
  char* ws = (char*)d_ws;
  int* tt    = (int*)ws;   ws += 16384;
  u16* xn    = (u16*)ws;   ws += (size_t)4096 * 1024 * 2;   // [B*T][DIM]
  u16* medb  = (u16*)ws;   ws += (size_t)4096 * 1024 * 2;   // [B*TM][DIM]
  u16* Wqt   = (u16*)ws;   ws += (size_t)1024 * 1024 * 2;   // [INNER][DIM]
  u16* Wkvt  = (u16*)ws;   ws += (size_t)2048 * 1024 * 2;   // [2*INNER][DIM]
  u16* Woutt = (u16*)ws;   ws += (size_t)1024 * 1024 * 2;   // [DIM][INNER]
  u16* qb    = (u16*)ws;   ws += (size_t)4096 * 1024 * 2;   // [B*T][INNER]
  u16* kB    = (u16*)ws;   ws += (size_t)4096 * 1024 * 2;   // [B,H,TM,64] token-major
  u16* vT    = (u16*)ws;   ws += (size_t)4096 * 1024 * 2;   // [B,H,64,TM] dim-major
  u16* ao    = (u16*)ws;   ws += (size_t)4096 * 1024 * 2;   // [B*T][INNER]

  scan_kernel<<<1, 256, 0, stream>>>(locs, tt);
  ln_kernel<<<BATCH * TTEXT, 256, 0, stream>>>(x, gamma, beta, xn);
  cvt_kernel<<<4096, 256, 0, stream>>>(media, medb);
  transpose3<<<dim3(32, 32, 4), 256, 0, stream>>>(Wq, Wkv, Wout, Wqt, Wkvt, Woutt);
  mgemm<0, 64><<<dim3(32, 16), 256, 0, stream>>>(xn,   Wqt,   qb,    nullptr, 4096, 1024, 1024);
  mgemm<2,128><<<dim3(32, 16), 256, 0, stream>>>(medb, Wkvt,  kB,    vT,      4096, 2048, 1024);
  attn_kernel<<<dim3(1024), 256, 0, stream>>>(qb, kB, vT, tt, ao);
  mgemm<1, 64><<<dim3(32, 16), 256, 0, stream>>>(ao,   Woutt, d_out, nullptr, 4096, 1024, 1024);
}